// Round 12
// baseline (230.293 us; speedup 1.0000x reference)
//
#include <hip/hip_runtime.h>
#include <math.h>

typedef unsigned short ushort_t;
typedef float f32x4 __attribute__((ext_vector_type(4)));
typedef __bf16 bf16x8 __attribute__((ext_vector_type(8)));

#define DEVFN __device__ __forceinline__

DEVFN ushort_t f2bf(float f) {
  unsigned int u = __float_as_uint(f);
  u += 0x7FFFu + ((u >> 16) & 1u);   // round-to-nearest-even
  return (ushort_t)(u >> 16);
}
DEVFN float bf2f(ushort_t u) { return __uint_as_float((unsigned int)u << 16); }

DEVFN void gload(const ushort_t* src, char* dst) {
  __builtin_amdgcn_global_load_lds(
      (const __attribute__((address_space(1))) unsigned int*)src,
      (__attribute__((address_space(3))) unsigned int*)dst, 16, 0, 0);
}

#define N_TOK  2048
#define HDIM   768
#define TCOLS  8448     // 2*I + 3*H
#define FFI    3072
#define NHEADS 12
#define HD     64
#define NSEG   8
#define SEGLEN 256
#define ABCOLS 3840     // H + I
#define NPART  6
#define KCHUNK 768
#define KT768  24       // 768/32 k-tiles

// Fragment-tile layout for GEMM1 operands: [rows/16][768/32][16][32] bf16.
// Element (row, k) -> ((row>>4)*24 + (k>>5))*512 + (row&15)*32 + (k&31).

// ---------------------------------------------------------------- transpose 64x32: LINEAR output (woutT)
DEVFN void transpose_tile(const float* __restrict__ in, ushort_t* __restrict__ out,
                          int R, int C, int tr, int tc, int tid, char* smem) {
  ushort_t (*tile)[66] = (ushort_t(*)[66])smem;
  const int tx = tid & 31, ty = tid >> 5;   // 32 x 8
#pragma unroll
  for (int i = 0; i < 8; ++i) {
    const int r = ty + i * 8;
    tile[tx][r] = f2bf(in[(size_t)(tr + r) * C + tc + tx]);
  }
  __syncthreads();
#pragma unroll
  for (int i = 0; i < 4; ++i) {
    const int c = ty + i * 8;
    ushort2 pk; pk.x = tile[c][2 * tx]; pk.y = tile[c][2 * tx + 1];
    *(ushort2*)(out + (size_t)(tc + c) * R + tr + 2 * tx) = pk;
  }
}

// ---------------------------------------------------------------- transpose 64x32: FRAGMENT-TILED output (winT)
// in: Win f32 [768(K) x TCOLS(N)]; out frag layout over (N-row, K-col), K total 768.
DEVFN void transpose_tile_frag(const float* __restrict__ in, ushort_t* __restrict__ out,
                               int C, int tr, int tc, int tid, char* smem) {
  ushort_t (*tile)[66] = (ushort_t(*)[66])smem;
  const int tx = tid & 31, ty = tid >> 5;   // 32 x 8
#pragma unroll
  for (int i = 0; i < 8; ++i) {
    const int r = ty + i * 8;
    tile[tx][r] = f2bf(in[(size_t)(tr + r) * C + tc + tx]);
  }
  __syncthreads();
#pragma unroll
  for (int i = 0; i < 4; ++i) {
    const int c = ty + i * 8;              // 0..31
    const int nrow = tc + c;               // N index
    const int kcol = tr + 2 * tx;          // K index (even)
    ushort2 pk; pk.x = tile[c][2 * tx]; pk.y = tile[c][2 * tx + 1];
    const size_t off = ((size_t)(nrow >> 4) * KT768 + (kcol >> 5)) * 512
                       + (nrow & 15) * 32 + (kcol & 31);
    *(ushort2*)(out + off) = pk;
  }
}

// ---------------------------------------------------------------- preamble: winT-0 frag transpose + rms_init
__global__ __launch_bounds__(256) void preamble(
    const float* __restrict__ Win, ushort_t* __restrict__ winT,
    const float* __restrict__ embed, const int* __restrict__ tokens,
    const float* __restrict__ ages,
    const float* __restrict__ in_nw, const float* __restrict__ layer_nw,
    const float* __restrict__ time_data,
    float* __restrict__ x, ushort_t* __restrict__ hbuf, float2* __restrict__ sctab) {
  const int tid = threadIdx.x;
  if (blockIdx.x < 3168) {
    __shared__ char tsmem[32 * 66 * 2];
    const int id = blockIdx.x;
    transpose_tile_frag(Win, winT, TCOLS, (id / 264) * 64, (id % 264) * 32, tid, tsmem);
    return;
  }
  const int row = blockIdx.x - 3168;
  if (tid < 32) {
    const int k = tid;
    const float e = (2.0f * (float)k) / 31.0f;
    const float t = ages[row] * expf(-e * logf(10000.0f));
    float2 cs; cs.x = cosf(t); cs.y = sinf(t);
    sctab[row * HD + 2 * k] = cs;
    sctab[row * HD + 2 * k + 1] = cs;
  }
  __shared__ float part[4];
  const float* src = embed + (size_t)tokens[row] * HDIM;
  float4 v = {0.f, 0.f, 0.f, 0.f};
  const int c0 = tid * 4;
  if (tid < 192) v = *(const float4*)(src + c0);
  float ss = v.x * v.x + v.y * v.y + v.z * v.z + v.w * v.w;
#pragma unroll
  for (int off = 1; off < 64; off <<= 1) ss += __shfl_xor(ss, off);
  if ((tid & 63) == 0) part[tid >> 6] = ss;
  __syncthreads();
  const float rs = rsqrtf((part[0] + part[1] + part[2] + part[3]) * (1.0f / HDIM) + 1e-6f);
  float4 y = {0.f, 0.f, 0.f, 0.f};
  if (tid < 192) {
    y.x = v.x * rs * in_nw[c0]; y.y = v.y * rs * in_nw[c0 + 1];
    y.z = v.z * rs * in_nw[c0 + 2]; y.w = v.w * rs * in_nw[c0 + 3];
    *(float4*)(x + (size_t)row * HDIM + c0) = y;
  }
  float ss2 = y.x * y.x + y.y * y.y + y.z * y.z + y.w * y.w;
#pragma unroll
  for (int off = 1; off < 64; off <<= 1) ss2 += __shfl_xor(ss2, off);
  __syncthreads();
  if ((tid & 63) == 0) part[tid >> 6] = ss2;
  __syncthreads();
  const float rs2 = rsqrtf((part[0] + part[1] + part[2] + part[3]) * (1.0f / HDIM) + 1e-6f);
  if (tid < 192) {
    float val[4];
#pragma unroll
    for (int j = 0; j < 4; ++j) {
      const int c = c0 + j;
      float vv = ((const float*)&y)[j] * rs2 * layer_nw[c];
      if (c >= HDIM - 4) {
        const float td = time_data[row * 2 + (c & 1)];
        vv = (c >= HDIM - 2) ? td * td : td;
      }
      val[j] = vv;
    }
    ushort4 pk;
    pk.x = f2bf(val[0]); pk.y = f2bf(val[1]); pk.z = f2bf(val[2]); pk.w = f2bf(val[3]);
    const size_t off = ((size_t)(row >> 4) * KT768 + (c0 >> 5)) * 512
                       + (row & 15) * 32 + (c0 & 31);
    *(ushort4*)(hbuf + off) = pk;
  }
}

// ---------------------------------------------------------------- fused reduce + residual + rms (hbuf frag out)
__global__ __launch_bounds__(256) void rms_fused(
    const ushort_t* __restrict__ cpartb, float* __restrict__ x,
    const float* __restrict__ w, const float* __restrict__ time_data,
    float* __restrict__ out_f32, ushort_t* __restrict__ out_bf16, const int mode) {
  const int row = blockIdx.x;
  const size_t stride = (size_t)N_TOK * HDIM;
  const int tid = threadIdx.x;
  const int c0 = tid * 4;
  float4 s = {0.f, 0.f, 0.f, 0.f};
  if (tid < 192) {
    s = *(const float4*)(x + (size_t)row * HDIM + c0);
#pragma unroll
    for (int z = 0; z < NPART; ++z) {
      const ushort4 p = *(const ushort4*)(cpartb + z * stride + (size_t)row * HDIM + c0);
      s.x += bf2f(p.x); s.y += bf2f(p.y); s.z += bf2f(p.z); s.w += bf2f(p.w);
    }
    if (mode == 1) *(float4*)(x + (size_t)row * HDIM + c0) = s;
  }
  float ss = s.x * s.x + s.y * s.y + s.z * s.z + s.w * s.w;
#pragma unroll
  for (int off = 1; off < 64; off <<= 1) ss += __shfl_xor(ss, off);
  __shared__ float part[4];
  if ((tid & 63) == 0) part[tid >> 6] = ss;
  __syncthreads();
  const float rs = rsqrtf((part[0] + part[1] + part[2] + part[3]) * (1.0f / HDIM) + 1e-6f);
  if (tid < 192) {
    float val[4];
#pragma unroll
    for (int j = 0; j < 4; ++j) {
      const int c = c0 + j;
      float vv = ((const float*)&s)[j] * rs * w[c];
      if (mode == 1 && c >= HDIM - 4) {
        const float td = time_data[row * 2 + (c & 1)];
        vv = (c >= HDIM - 2) ? td * td : td;
      }
      val[j] = vv;
    }
    if (mode == 1) {
      ushort4 pk;
      pk.x = f2bf(val[0]); pk.y = f2bf(val[1]); pk.z = f2bf(val[2]); pk.w = f2bf(val[3]);
      const size_t off = ((size_t)(row >> 4) * KT768 + (c0 >> 5)) * 512
                         + (row & 15) * 32 + (c0 & 31);
      *(ushort4*)(out_bf16 + off) = pk;
    } else {
      float4 o; o.x = val[0]; o.y = val[1]; o.z = val[2]; o.w = val[3];
      *(float4*)(out_f32 + (size_t)row * HDIM + c0) = o;
    }
  }
}

// ---------------------------------------------------------------- GEMM1: LDS-free, fragment-tiled direct loads
#define G1_NT 24

// extra blocks (bid>=704): e<1440 -> Wout->woutT (linear); else Win lyr1 -> winT lyr1 (frag)
__global__ __launch_bounds__(256, 3) void gemm1f(
    const ushort_t* __restrict__ A, const ushort_t* __restrict__ BT,
    const float2* __restrict__ sctab,
    ushort_t* __restrict__ ab, ushort_t* __restrict__ qr,
    ushort_t* __restrict__ kr, ushort_t* __restrict__ vT,
    const float* __restrict__ tj1_src, ushort_t* __restrict__ tj1_dst,
    const float* __restrict__ tj2_src, ushort_t* __restrict__ tj2_dst) {
  __shared__ char tsmem[32 * 66 * 2];
  const int tid = threadIdx.x;
  const int bid = (int)blockIdx.x;
  if (bid >= 704) {
    int e = bid - 704;
    if (e < 1440)
      transpose_tile(tj1_src, tj1_dst, ABCOLS, HDIM, (e / 24) * 64, (e % 24) * 32, tid, tsmem);
    else {
      e -= 1440;
      transpose_tile_frag(tj2_src, tj2_dst, TCOLS, (e / 264) * 64, (e % 264) * 32, tid, tsmem);
    }
    return;
  }
  const int l = tid & 63, l15 = l & 15, l4 = l >> 4;
  const int wid = tid >> 6, wr = wid >> 1, wc = wid & 1;
  const int wg = (bid & 7) * 88 + (bid >> 3);
  const int nt = wg >> 4, mt = wg & 15;
  const int m0 = mt * 128, n0 = nt * 192;

  const int laneoff = l15 * 32 + l4 * 8;
  // A fragment base pointers: m-tile index mt*8 + wr*4 + m
  const ushort_t* abase = A + ((size_t)(mt * 8 + wr * 4) * KT768) * 512 + laneoff;
  // B fragment base pointers: virtual n-tile -> real via x1/x2 interleave map
  const ushort_t* bbase[6];
#pragma unroll
  for (int n = 0; n < 6; ++n) {
    const int vt = nt * 12 + wc * 6 + n;           // virtual 16-col tile
    const int rt = (vt < 384) ? ((vt & 1) * 192 + (vt >> 1)) : vt;
    bbase[n] = BT + ((size_t)rt * KT768) * 512 + laneoff;
  }

  f32x4 acc[4][6] = {};

  for (int t = 0; t < G1_NT; ++t) {
    bf16x8 a4[4], b6[6];
#pragma unroll
    for (int m = 0; m < 4; ++m)
      a4[m] = *(const bf16x8*)(abase + (size_t)m * KT768 * 512 + t * 512);
#pragma unroll
    for (int n = 0; n < 6; ++n)
      b6[n] = *(const bf16x8*)(bbase[n] + t * 512);
#pragma unroll
    for (int m = 0; m < 4; ++m)
#pragma unroll
      for (int n = 0; n < 6; ++n)
        acc[m][n] = __builtin_amdgcn_mfma_f32_16x16x32_bf16(a4[m], b6[n], acc[m][n], 0, 0, 0);
  }

  if (nt < 32) {
#pragma unroll
    for (int m = 0; m < 4; ++m)
#pragma unroll
      for (int np = 0; np < 3; ++np) {
        const int colj = (nt * 6 + wc * 3 + np) * 16 + l15;
#pragma unroll
        for (int r = 0; r < 4; ++r) {
          const float x1 = acc[m][2 * np][r], x2 = acc[m][2 * np + 1][r];
          const float sv = x1 / (1.f + __expf(-x1)) * x2;
          const int row = m0 + wr * 64 + m * 16 + l4 * 4 + r;
          ab[(size_t)row * ABCOLS + HDIM + colj] = f2bf(sv);
        }
      }
  } else {
#pragma unroll
    for (int n = 0; n < 6; ++n) {
      const int gcol = (nt - 32) * 192 + wc * 96 + n * 16;
      const int g = gcol >> 6;
      const int typ = g / NHEADS, h = g - typ * NHEADS;
      const int d = (gcol & 63) + l15;
      if (typ == 2) {
#pragma unroll
        for (int m = 0; m < 4; ++m) {
          ushort4 pk;
          pk.x = f2bf(acc[m][n][0]); pk.y = f2bf(acc[m][n][1]);
          pk.z = f2bf(acc[m][n][2]); pk.w = f2bf(acc[m][n][3]);
          const int row0 = m0 + wr * 64 + m * 16 + l4 * 4;
          *(ushort4*)(vT + ((size_t)h * HD + d) * N_TOK + row0) = pk;
        }
      } else {
        ushort_t* dst = (typ == 0) ? qr : kr;
        const float sgn = (l15 & 1) ? 1.f : -1.f;
#pragma unroll
        for (int m = 0; m < 4; ++m)
#pragma unroll
          for (int r = 0; r < 4; ++r) {
            const float val = acc[m][n][r];
            const float partner = __shfl_xor(val, 1);
            const int row = m0 + wr * 64 + m * 16 + l4 * 4 + r;
            const float2 cs = sctab[row * HD + d];
            dst[((size_t)h * N_TOK + row) * HD + d] = f2bf(val * cs.x + sgn * partner * cs.y);
          }
      }
    }
  }
}

// ---------------------------------------------------------------- GEMM2 body: unchanged (LDS, single-barrier)
#define G2_BUF 40960          // A 16KB + B 24KB

DEVFN int swz128(int p) { return p ^ (((p >> 7) & 7) << 4); }

DEVFN void g2_stage(const ushort_t* __restrict__ A, const ushort_t* __restrict__ BT,
                    int m0, int n0, int kt_el, char* buf, int tid) {
#pragma unroll
  for (int i = 0; i < 10; ++i) {
    const int p = i * 4096 + tid * 16;
    const bool isA = p < 16384;
    const int q = swz128(isA ? p : p - 16384);
    const int row = q >> 7, colel = (q & 127) >> 1;
    const ushort_t* src = (isA ? A + (size_t)(m0 + row) * ABCOLS
                               : BT + (size_t)(n0 + row) * ABCOLS) + kt_el + colel;
    gload(src, buf + i * 4096 + ((tid >> 6) << 10));
  }
}

DEVFN void g2_body(const ushort_t* __restrict__ A, const ushort_t* __restrict__ BT,
                   char* smem, int m0, int n0, int kt0, int NT,
                   ushort_t* __restrict__ outp, int tid) {
  const int l = tid & 63, l15 = l & 15, l4 = l >> 4;
  const int w = tid >> 6, wr = w >> 1, wc = w & 1;
  f32x4 acc[4][6] = {};

  g2_stage(A, BT, m0, n0, kt0, smem, tid);
  asm volatile("s_waitcnt vmcnt(0)" ::: "memory");
  __builtin_amdgcn_s_barrier();

  for (int t = 0; t < NT; ++t) {
    const char* bufA = smem + (t & 1) * G2_BUF;
    const char* bufB = bufA + 16384;
    if (t + 1 < NT) {
      g2_stage(A, BT, m0, n0, kt0 + (t + 1) * 64, smem + ((t + 1) & 1) * G2_BUF, tid);
      __builtin_amdgcn_sched_barrier(0);
    }
#pragma unroll
    for (int kk = 0; kk < 2; ++kk) {
      bf16x8 af[4], bv[6];
#pragma unroll
      for (int mi = 0; mi < 4; ++mi) {
        const int p = (wr * 64 + mi * 16 + l15) * 128 + kk * 64 + l4 * 16;
        af[mi] = *(const bf16x8*)(bufA + swz128(p));
      }
#pragma unroll
      for (int ni = 0; ni < 6; ++ni) {
        const int p = (wc * 96 + ni * 16 + l15) * 128 + kk * 64 + l4 * 16;
        bv[ni] = *(const bf16x8*)(bufB + swz128(p));
      }
#pragma unroll
      for (int mi = 0; mi < 4; ++mi)
#pragma unroll
        for (int ni = 0; ni < 6; ++ni)
          acc[mi][ni] = __builtin_amdgcn_mfma_f32_16x16x32_bf16(af[mi], bv[ni], acc[mi][ni], 0, 0, 0);
    }

    if (t + 1 < NT) {
      asm volatile("s_waitcnt vmcnt(0)" ::: "memory");
      __builtin_amdgcn_s_barrier();
    }
  }

#pragma unroll
  for (int mi = 0; mi < 4; ++mi)
#pragma unroll
    for (int ni = 0; ni < 6; ++ni)
#pragma unroll
      for (int r = 0; r < 4; ++r) {
        const int row = m0 + wr * 64 + mi * 16 + l4 * 4 + r;
        const int col = n0 + wc * 96 + ni * 16 + l15;
        outp[(size_t)row * HDIM + col] = f2bf(acc[mi][ni][r]);
      }
}

// ---------------------------------------------------------------- attention one q-tile (wave-private)
DEVFN void attn_one(const ushort_t* __restrict__ qr, const ushort_t* __restrict__ kr,
                    const ushort_t* __restrict__ vT, ushort_t* __restrict__ ab,
                    int h, int seg, int qt, ushort_t* Pw, int l15, int l4) {
  const int qrow0 = seg * SEGLEN + qt * 16;
  bf16x8 aq[2];
#pragma unroll
  for (int kk = 0; kk < 2; ++kk)
    aq[kk] = *(const bf16x8*)(qr + ((size_t)h * N_TOK + qrow0 + l15) * HD + kk * 32 + l4 * 8);

  f32x4 o[4] = {};
  float m_run[4], l_run[4];
#pragma unroll
  for (int r = 0; r < 4; ++r) { m_run[r] = -1e30f; l_run[r] = 0.f; }

  const int kbmax = qt >> 2;
  for (int kb = 0; kb <= kbmax; ++kb) {
    bf16x8 bk[4][2];
#pragma unroll
    for (int ni = 0; ni < 4; ++ni)
#pragma unroll
      for (int kk = 0; kk < 2; ++kk)
        bk[ni][kk] = *(const bf16x8*)(kr + ((size_t)h * N_TOK + seg * SEGLEN + kb * 64 + ni * 16 + l15) * HD + kk * 32 + l4 * 8);
    f32x4 s[4] = {};
#pragma unroll
    for (int ni = 0; ni < 4; ++ni)
#pragma unroll
      for (int kk = 0; kk < 2; ++kk)
        s[ni] = __builtin_amdgcn_mfma_f32_16x16x32_bf16(aq[kk], bk[ni][kk], s[ni], 0, 0, 0);

    const bool diag = (kb == kbmax);
#pragma unroll
    for (int ni = 0; ni < 4; ++ni)
#pragma unroll
      for (int r = 0; r < 4; ++r) {
        float v = s[ni][r] * 0.125f;
        if (diag) {
          const int qrow = qt * 16 + l4 * 4 + r;
          const int jcol = kb * 64 + ni * 16 + l15;
          if (jcol > qrow) v = -1e30f;
        }
        s[ni][r] = v;
      }

    float sc_[4];
#pragma unroll
    for (int r = 0; r < 4; ++r) {
      float pm = fmaxf(fmaxf(s[0][r], s[1][r]), fmaxf(s[2][r], s[3][r]));
      pm = fmaxf(pm, __shfl_xor(pm, 1));
      pm = fmaxf(pm, __shfl_xor(pm, 2));
      pm = fmaxf(pm, __shfl_xor(pm, 4));
      pm = fmaxf(pm, __shfl_xor(pm, 8));
      const float mn = fmaxf(m_run[r], pm);
      sc_[r] = __expf(m_run[r] - mn);
      m_run[r] = mn;
    }
#pragma unroll
    for (int ni = 0; ni < 4; ++ni)
#pragma unroll
      for (int r = 0; r < 4; ++r)
        s[ni][r] = __expf(s[ni][r] - m_run[r]);
#pragma unroll
    for (int r = 0; r < 4; ++r) {
      float ls = s[0][r] + s[1][r] + s[2][r] + s[3][r];
      ls += __shfl_xor(ls, 1);
      ls += __shfl_xor(ls, 2);
      ls += __shfl_xor(ls, 4);
      ls += __shfl_xor(ls, 8);
      l_run[r] = l_run[r] * sc_[r] + ls;
    }
#pragma unroll
    for (int ni = 0; ni < 4; ++ni)
#pragma unroll
      for (int r = 0; r < 4; ++r)
        o[ni][r] *= sc_[r];

#pragma unroll
    for (int ni = 0; ni < 4; ++ni)
#pragma unroll
      for (int r = 0; r < 4; ++r)
        Pw[(l4 * 4 + r) * 64 + ni * 16 + l15] = f2bf(s[ni][r]);

    bf16x8 pa[2], bv[4][2];
#pragma unroll
    for (int k2 = 0; k2 < 2; ++k2)
      pa[k2] = *(const bf16x8*)(&Pw[l15 * 64 + k2 * 32 + l4 * 8]);
#pragma unroll
    for (int ni = 0; ni < 4; ++ni)
#pragma unroll
      for (int k2 = 0; k2 < 2; ++k2)
        bv[ni][k2] = *(const bf16x8*)(vT + ((size_t)h * HD + ni * 16 + l15) * N_TOK + seg * SEGLEN + kb * 64 + k2 * 32 + l4 * 8);
#pragma unroll
    for (int ni = 0; ni < 4; ++ni)
#pragma unroll
      for (int k2 = 0; k2 < 2; ++k2)
        o[ni] = __builtin_amdgcn_mfma_f32_16x16x32_bf16(pa[k2], bv[ni][k2], o[ni], 0, 0, 0);
  }

#pragma unroll
  for (int ni = 0; ni < 4; ++ni)
#pragma unroll
    for (int r = 0; r < 4; ++r) {
      const int row = qrow0 + l4 * 4 + r;
      const int col = h * HD + ni * 16 + l15;
      ab[(size_t)row * ABCOLS + col] = f2bf(o[ni][r] / l_run[r]);
    }
}

// ---------------------------------------------------------------- fused mid: 448 blocks + extra transposes (linear)
__global__ __launch_bounds__(256, 2) void fused_mid(
    const ushort_t* __restrict__ ab, const ushort_t* __restrict__ woutT,
    ushort_t* __restrict__ cpartb,
    const ushort_t* __restrict__ qr, const ushort_t* __restrict__ kr,
    const ushort_t* __restrict__ vT, ushort_t* __restrict__ ab_out,
    const float* __restrict__ tj_src, ushort_t* __restrict__ tj_dst) {
  __shared__ __align__(16) char smem[2 * G2_BUF];     // 80 KiB
  const int b = (int)blockIdx.x;
  const int tid = threadIdx.x;
  if (b >= 448) {
    const int e = b - 448;
    transpose_tile(tj_src, tj_dst, ABCOLS, HDIM, (e / 24) * 64, (e % 24) * 32, tid, smem);
    return;
  }
  const int sel = b % 7;
  if (sel < 3) {
    const int a = (b / 7) * 3 + sel;      // 0..191
    const int h = a % NHEADS;
    const int r2 = a / NHEADS;            // 0..15
    const int seg = r2 & 7, p = r2 >> 3;  // p in {0,1}
    const int w = tid >> 6, l = tid & 63;
    const int l15 = l & 15, l4 = l >> 4;
    ushort_t* Pw = (ushort_t*)smem + w * (16 * 64);
    attn_one(qr, kr, vT, ab_out, h, seg, p * 4 + w, Pw, l15, l4);
    attn_one(qr, kr, vT, ab_out, h, seg, (3 - p) * 4 + w, Pw, l15, l4);
  } else {
    const int f = (b / 7) * 4 + (sel - 3);   // 0..255
    const int z = 1 + (f >> 6);              // ff chunks 1..4
    const int rem = f & 63;
    const int n0 = (rem & 3) * 192, m0 = (rem >> 2) * 128;
    g2_body(ab, woutT, smem, m0, n0, z * KCHUNK, 12,
            cpartb + (size_t)(z - 1) * N_TOK * HDIM, tid);
  }
}

// ---------------------------------------------------------------- gemm2 attn-column chunk (K 0..768, split in 2)
__global__ __launch_bounds__(256, 2) void gemm2_z0(
    const ushort_t* __restrict__ ab, const ushort_t* __restrict__ woutT,
    ushort_t* __restrict__ cpartb) {
  __shared__ __align__(16) char smem[2 * G2_BUF];
  const int b = (int)blockIdx.x;
  const int half = b >> 6, rem = b & 63;
  const int n0 = (rem & 3) * 192, m0 = (rem >> 2) * 128;
  g2_body(ab, woutT, smem, m0, n0, half * 384, 6,
          cpartb + (size_t)(4 + half) * N_TOK * HDIM, threadIdx.x);
}

// ----------------------------------------------------------------
extern "C" void kernel_launch(void* const* d_in, const int* in_sizes, int n_in,
                              void* d_out, int out_size, void* d_ws, size_t ws_size,
                              hipStream_t stream) {
  const int*   tokens   = (const int*)d_in[0];
  const float* ages     = (const float*)d_in[1];
  const float* time_d   = (const float*)d_in[2];
  const float* embed    = (const float*)d_in[4];
  const float* in_nw    = (const float*)d_in[5];
  const float* out_nw   = (const float*)d_in[6];
  const float* layer_nw = (const float*)d_in[7];
  const float* Win      = (const float*)d_in[8];
  const float* Wout     = (const float*)d_in[9];
  float* out = (float*)d_out;

  char* ws = (char*)d_ws;
  float*    x      = (float*)   (ws + 0);            //  6,291,456
  ushort_t* hbuf   = (ushort_t*)(ws + 6291456);      //  3,145,728 (frag layout)
  float2*   sctab  = (float2*)  (ws + 9437184);      //  1,048,576
  ushort_t* cpartb = (ushort_t*)(ws + 10485760);     // 18,874,368 (6 bf16 slices)
  ushort_t* ab     = (ushort_t*)(ws + 29360128);     // 15,728,640
  ushort_t* qrb    = (ushort_t*)(ws + 45088768);     //  3,145,728
  ushort_t* krb    = (ushort_t*)(ws + 48234496);     //  3,145,728
  ushort_t* vTb    = (ushort_t*)(ws + 51380224);     //  3,145,728
  ushort_t* winT   = (ushort_t*)(ws + 54525952);     // 25,952,256 (frag layout)
  ushort_t* woutT  = (ushort_t*)(ws + 80478208);     // 11,796,480 (linear)

  const size_t winStride  = (size_t)TCOLS * HDIM;
  const size_t woutStride = (size_t)HDIM * ABCOLS;

  preamble<<<dim3(5216), dim3(256), 0, stream>>>(Win, winT, embed, tokens, ages,
                                                 in_nw, layer_nw, time_d, x, hbuf, sctab);

  for (int lyr = 0; lyr < 2; ++lyr) {
    if (lyr == 0) {
      gemm1f<<<dim3(704 + 4608), dim3(256), 0, stream>>>(
          hbuf, winT, sctab, ab, qrb, krb, vTb,
          Wout, woutT, Win + winStride, winT + winStride);
      fused_mid<<<dim3(448 + 1440), dim3(256), 0, stream>>>(
          ab, woutT, cpartb, qrb, krb, vTb, ab,
          Wout + woutStride, woutT + woutStride);
    } else {
      gemm1f<<<dim3(704), dim3(256), 0, stream>>>(
          hbuf, winT + winStride, sctab, ab, qrb, krb, vTb,
          nullptr, nullptr, nullptr, nullptr);
      fused_mid<<<dim3(448), dim3(256), 0, stream>>>(
          ab, woutT + woutStride, cpartb, qrb, krb, vTb, ab,
          nullptr, nullptr);
    }
    gemm2_z0<<<dim3(128), dim3(256), 0, stream>>>(ab, woutT + lyr * woutStride, cpartb);
    if (lyr == 0)
      rms_fused<<<dim3(N_TOK), dim3(256), 0, stream>>>(cpartb, x, layer_nw + HDIM, time_d,
                                                       nullptr, hbuf, 1);
    else
      rms_fused<<<dim3(N_TOK), dim3(256), 0, stream>>>(cpartb, x, out_nw, nullptr,
                                                       out, nullptr, 2);
  }
}

// Round 13
// 225.950 us; speedup vs baseline: 1.0192x; 1.0192x over previous
//
#include <hip/hip_runtime.h>
#include <math.h>

typedef unsigned short ushort_t;
typedef float f32x4 __attribute__((ext_vector_type(4)));
typedef __bf16 bf16x8 __attribute__((ext_vector_type(8)));

#define DEVFN __device__ __forceinline__

DEVFN ushort_t f2bf(float f) {
  unsigned int u = __float_as_uint(f);
  u += 0x7FFFu + ((u >> 16) & 1u);   // round-to-nearest-even
  return (ushort_t)(u >> 16);
}
DEVFN float bf2f(ushort_t u) { return __uint_as_float((unsigned int)u << 16); }

DEVFN void gload(const ushort_t* src, char* dst) {
  __builtin_amdgcn_global_load_lds(
      (const __attribute__((address_space(1))) unsigned int*)src,
      (__attribute__((address_space(3))) unsigned int*)dst, 16, 0, 0);
}

#define N_TOK  2048
#define HDIM   768
#define TCOLS  8448     // 2*I + 3*H
#define FFI    3072
#define NHEADS 12
#define HD     64
#define NSEG   8
#define SEGLEN 256
#define ABCOLS 3840     // H + I
#define NPART  6
#define KCHUNK 768

// ---------------------------------------------------------------- 64x32 transpose tile (tid<256 active; sync block-wide)
DEVFN void transpose_tile(const float* __restrict__ in, ushort_t* __restrict__ out,
                          int R, int C, int tr, int tc, int tid, char* smem) {
  ushort_t (*tile)[66] = (ushort_t(*)[66])smem;
  const int tx = tid & 31, ty = (tid >> 5) & 7;   // 32 x 8
  if (tid < 256) {
#pragma unroll
    for (int i = 0; i < 8; ++i) {
      const int r = ty + i * 8;
      tile[tx][r] = f2bf(in[(size_t)(tr + r) * C + tc + tx]);
    }
  }
  __syncthreads();
  if (tid < 256) {
#pragma unroll
    for (int i = 0; i < 4; ++i) {
      const int c = ty + i * 8;
      ushort2 pk; pk.x = tile[c][2 * tx]; pk.y = tile[c][2 * tx + 1];
      *(ushort2*)(out + (size_t)(tc + c) * R + tr + 2 * tx) = pk;
    }
  }
}

// ---------------------------------------------------------------- preamble: winT-0 transpose + rms_init
__global__ __launch_bounds__(256) void preamble(
    const float* __restrict__ Win, ushort_t* __restrict__ winT,
    const float* __restrict__ embed, const int* __restrict__ tokens,
    const float* __restrict__ ages,
    const float* __restrict__ in_nw, const float* __restrict__ layer_nw,
    const float* __restrict__ time_data,
    float* __restrict__ x, ushort_t* __restrict__ hbuf, float2* __restrict__ sctab) {
  const int tid = threadIdx.x;
  if (blockIdx.x < 3168) {
    __shared__ char tsmem[32 * 66 * 2];
    const int id = blockIdx.x;
    transpose_tile(Win, winT, HDIM, TCOLS, (id / 264) * 64, (id % 264) * 32, tid, tsmem);
    return;
  }
  const int row = blockIdx.x - 3168;
  if (tid < 32) {
    const int k = tid;
    const float e = (2.0f * (float)k) / 31.0f;
    const float t = ages[row] * expf(-e * logf(10000.0f));
    float2 cs; cs.x = cosf(t); cs.y = sinf(t);
    sctab[row * HD + 2 * k] = cs;
    sctab[row * HD + 2 * k + 1] = cs;
  }
  __shared__ float part[4];
  const float* src = embed + (size_t)tokens[row] * HDIM;
  float4 v = {0.f, 0.f, 0.f, 0.f};
  const int c0 = tid * 4;
  if (tid < 192) v = *(const float4*)(src + c0);
  float ss = v.x * v.x + v.y * v.y + v.z * v.z + v.w * v.w;
#pragma unroll
  for (int off = 1; off < 64; off <<= 1) ss += __shfl_xor(ss, off);
  if ((tid & 63) == 0) part[tid >> 6] = ss;
  __syncthreads();
  const float rs = rsqrtf((part[0] + part[1] + part[2] + part[3]) * (1.0f / HDIM) + 1e-6f);
  float4 y = {0.f, 0.f, 0.f, 0.f};
  if (tid < 192) {
    y.x = v.x * rs * in_nw[c0]; y.y = v.y * rs * in_nw[c0 + 1];
    y.z = v.z * rs * in_nw[c0 + 2]; y.w = v.w * rs * in_nw[c0 + 3];
    *(float4*)(x + (size_t)row * HDIM + c0) = y;
  }
  float ss2 = y.x * y.x + y.y * y.y + y.z * y.z + y.w * y.w;
#pragma unroll
  for (int off = 1; off < 64; off <<= 1) ss2 += __shfl_xor(ss2, off);
  __syncthreads();
  if ((tid & 63) == 0) part[tid >> 6] = ss2;
  __syncthreads();
  const float rs2 = rsqrtf((part[0] + part[1] + part[2] + part[3]) * (1.0f / HDIM) + 1e-6f);
  if (tid < 192) {
    float val[4];
#pragma unroll
    for (int j = 0; j < 4; ++j) {
      const int c = c0 + j;
      float vv = ((const float*)&y)[j] * rs2 * layer_nw[c];
      if (c >= HDIM - 4) {
        const float td = time_data[row * 2 + (c & 1)];
        vv = (c >= HDIM - 2) ? td * td : td;
      }
      val[j] = vv;
    }
    ushort4 pk;
    pk.x = f2bf(val[0]); pk.y = f2bf(val[1]); pk.z = f2bf(val[2]); pk.w = f2bf(val[3]);
    *(ushort4*)(hbuf + (size_t)row * HDIM + c0) = pk;
  }
}

// ---------------------------------------------------------------- fused reduce(6 bf16 partials) + residual + rms
__global__ __launch_bounds__(256) void rms_fused(
    const ushort_t* __restrict__ cpartb, float* __restrict__ x,
    const float* __restrict__ w, const float* __restrict__ time_data,
    float* __restrict__ out_f32, ushort_t* __restrict__ out_bf16, const int mode) {
  const int row = blockIdx.x;
  const size_t stride = (size_t)N_TOK * HDIM;
  const int tid = threadIdx.x;
  const int c0 = tid * 4;
  float4 s = {0.f, 0.f, 0.f, 0.f};
  if (tid < 192) {
    s = *(const float4*)(x + (size_t)row * HDIM + c0);
#pragma unroll
    for (int z = 0; z < NPART; ++z) {
      const ushort4 p = *(const ushort4*)(cpartb + z * stride + (size_t)row * HDIM + c0);
      s.x += bf2f(p.x); s.y += bf2f(p.y); s.z += bf2f(p.z); s.w += bf2f(p.w);
    }
    if (mode == 1) *(float4*)(x + (size_t)row * HDIM + c0) = s;
  }
  float ss = s.x * s.x + s.y * s.y + s.z * s.z + s.w * s.w;
#pragma unroll
  for (int off = 1; off < 64; off <<= 1) ss += __shfl_xor(ss, off);
  __shared__ float part[4];
  if ((tid & 63) == 0) part[tid >> 6] = ss;
  __syncthreads();
  const float rs = rsqrtf((part[0] + part[1] + part[2] + part[3]) * (1.0f / HDIM) + 1e-6f);
  if (tid < 192) {
    float val[4];
#pragma unroll
    for (int j = 0; j < 4; ++j) {
      const int c = c0 + j;
      float vv = ((const float*)&s)[j] * rs * w[c];
      if (mode == 1 && c >= HDIM - 4) {
        const float td = time_data[row * 2 + (c & 1)];
        vv = (c >= HDIM - 2) ? td * td : td;
      }
      val[j] = vv;
    }
    if (mode == 1) {
      ushort4 pk;
      pk.x = f2bf(val[0]); pk.y = f2bf(val[1]); pk.z = f2bf(val[2]); pk.w = f2bf(val[3]);
      *(ushort4*)(out_bf16 + (size_t)row * HDIM + c0) = pk;
    } else {
      float4 o; o.x = val[0]; o.y = val[1]; o.z = val[2]; o.w = val[3];
      *(float4*)(out_f32 + (size_t)row * HDIM + c0) = o;
    }
  }
}

// ---------------------------------------------------------------- GEMM1: 128x256 tile, 8 waves, acc[4][4], BK=32
#define G1_NT 24
#define G1_ABYT 8192          // 128x32 bf16
#define G1_BUF  24576         // + 256x32 bf16 (16384)

DEVFN int swz64(int p) {
  const int g = ((p >> 6) & 3) ^ ((p >> 8) & 3);
  return p ^ (g << 4);
}
DEVFN int ffmap(int vr) {
  return (vr < 2 * FFI) ? ((((vr >> 4) & 1) * FFI) + ((vr >> 5) << 4) + (vr & 15)) : vr;
}

DEVFN void g1f_stage(const ushort_t* __restrict__ A, const ushort_t* __restrict__ BT,
                     int m0, int n0, int kt_el, char* buf, int tid) {
  {  // A: 8KB, one round (512 thr x 16B)
    const int q = swz64(tid * 16);
    gload(A + (size_t)(m0 + (q >> 6)) * HDIM + kt_el + ((q & 63) >> 1),
          buf + ((tid >> 6) << 10));
  }
#pragma unroll
  for (int i = 0; i < 2; ++i) {   // B: 16KB, two rounds
    const int q = swz64(i * 8192 + tid * 16);
    const int vr = n0 + (q >> 6);
    gload(BT + (size_t)ffmap(vr) * HDIM + kt_el + ((q & 63) >> 1),
          buf + G1_ABYT + i * 8192 + ((tid >> 6) << 10));
  }
}

// extra blocks (bid>=528): e<1440 -> Wout->woutT; else -> Win lyr1 -> winT lyr1
__global__ __launch_bounds__(512, 3) void gemm1f(
    const ushort_t* __restrict__ A, const ushort_t* __restrict__ BT,
    const float2* __restrict__ sctab,
    ushort_t* __restrict__ ab, ushort_t* __restrict__ qr,
    ushort_t* __restrict__ kr, ushort_t* __restrict__ vT,
    const float* __restrict__ tj1_src, ushort_t* __restrict__ tj1_dst,
    const float* __restrict__ tj2_src, ushort_t* __restrict__ tj2_dst) {
  __shared__ __align__(16) char smem[2 * G1_BUF];     // 48 KiB
  const int tid = threadIdx.x;
  const int bid = (int)blockIdx.x;
  if (bid >= 528) {
    int e = bid - 528;
    if (e < 1440)
      transpose_tile(tj1_src, tj1_dst, ABCOLS, HDIM, (e / 24) * 64, (e % 24) * 32, tid, smem);
    else {
      e -= 1440;
      transpose_tile(tj2_src, tj2_dst, HDIM, TCOLS, (e / 264) * 64, (e % 264) * 32, tid, smem);
    }
    return;
  }
  const int l = tid & 63, l15 = l & 15, l4 = l >> 4;
  const int wid = tid >> 6, wr = wid >> 2, wc = wid & 3;   // 2x4 waves, 64x64 each
  const int wg = (bid & 7) * 66 + (bid >> 3);              // XCD-contiguous
  const int nt = wg >> 4, mt = wg & 15;                    // 33 N-tiles x 16 M-tiles
  const int m0 = mt * 128, n0 = nt * 256;

  f32x4 acc[4][4] = {};

  g1f_stage(A, BT, m0, n0, 0, smem, tid);
  asm volatile("s_waitcnt vmcnt(0)" ::: "memory");
  __builtin_amdgcn_s_barrier();

  for (int t = 0; t < G1_NT; ++t) {
    const char* bufA = smem + (t & 1) * G1_BUF;
    const char* bufB = bufA + G1_ABYT;
    if (t + 1 < G1_NT) {
      g1f_stage(A, BT, m0, n0, (t + 1) * 32, smem + ((t + 1) & 1) * G1_BUF, tid);
      __builtin_amdgcn_sched_barrier(0);
    }
    bf16x8 a4[4], b4[4];
#pragma unroll
    for (int m = 0; m < 4; ++m) {
      const int p = (wr * 64 + m * 16 + l15) * 64 + l4 * 16;
      a4[m] = *(const bf16x8*)(bufA + swz64(p));
    }
#pragma unroll
    for (int n = 0; n < 4; ++n) {
      const int p = (wc * 64 + n * 16 + l15) * 64 + l4 * 16;
      b4[n] = *(const bf16x8*)(bufB + swz64(p));
    }
#pragma unroll
    for (int m = 0; m < 4; ++m)
#pragma unroll
      for (int n = 0; n < 4; ++n)
        acc[m][n] = __builtin_amdgcn_mfma_f32_16x16x32_bf16(a4[m], b4[n], acc[m][n], 0, 0, 0);

    if (t + 1 < G1_NT) {
      asm volatile("s_waitcnt vmcnt(0)" ::: "memory");
      __builtin_amdgcn_s_barrier();
    }
  }

  if (nt < 24) {
    // ff: wave covers 4 virtual 16-col tiles = 2 silu pairs
#pragma unroll
    for (int m = 0; m < 4; ++m)
#pragma unroll
      for (int p_ = 0; p_ < 2; ++p_) {
        const int colj = (nt * 8 + wc * 2 + p_) * 16 + l15;   // [0, 3072)
#pragma unroll
        for (int r = 0; r < 4; ++r) {
          const float x1 = acc[m][2 * p_][r], x2 = acc[m][2 * p_ + 1][r];
          const float sv = x1 / (1.f + __expf(-x1)) * x2;
          const int row = m0 + wr * 64 + m * 16 + l4 * 4 + r;
          ab[(size_t)row * ABCOLS + HDIM + colj] = f2bf(sv);
        }
      }
  } else {
    // qkv: wave owns one 64-col head group
    const int g = (nt - 24) * 4 + wc;                // 0..35
    const int typ = g / NHEADS, h = g - typ * NHEADS;
    if (typ == 2) {
#pragma unroll
      for (int n = 0; n < 4; ++n) {
        const int d = n * 16 + l15;
#pragma unroll
        for (int m = 0; m < 4; ++m) {
          ushort4 pk;
          pk.x = f2bf(acc[m][n][0]); pk.y = f2bf(acc[m][n][1]);
          pk.z = f2bf(acc[m][n][2]); pk.w = f2bf(acc[m][n][3]);
          const int row0 = m0 + wr * 64 + m * 16 + l4 * 4;
          *(ushort4*)(vT + ((size_t)h * HD + d) * N_TOK + row0) = pk;
        }
      }
    } else {
      ushort_t* dst = (typ == 0) ? qr : kr;
      const float sgn = (l15 & 1) ? 1.f : -1.f;
#pragma unroll
      for (int n = 0; n < 4; ++n) {
        const int d = n * 16 + l15;
#pragma unroll
        for (int m = 0; m < 4; ++m)
#pragma unroll
          for (int r = 0; r < 4; ++r) {
            const float val = acc[m][n][r];
            const float partner = __shfl_xor(val, 1);
            const int row = m0 + wr * 64 + m * 16 + l4 * 4 + r;
            const float2 cs = sctab[row * HD + d];
            dst[((size_t)h * N_TOK + row) * HD + d] = f2bf(val * cs.x + sgn * partner * cs.y);
          }
      }
    }
  }
}

// ---------------------------------------------------------------- GEMM2 body: 128x192, BK=64, single-barrier 2-phase
#define G2_BUF 40960          // A 16KB + B 24KB

DEVFN int swz128(int p) { return p ^ (((p >> 7) & 7) << 4); }

DEVFN void g2_stage(const ushort_t* __restrict__ A, const ushort_t* __restrict__ BT,
                    int m0, int n0, int kt_el, char* buf, int tid) {
#pragma unroll
  for (int i = 0; i < 10; ++i) {
    const int p = i * 4096 + tid * 16;
    const bool isA = p < 16384;
    const int q = swz128(isA ? p : p - 16384);
    const int row = q >> 7, colel = (q & 127) >> 1;
    const ushort_t* src = (isA ? A + (size_t)(m0 + row) * ABCOLS
                               : BT + (size_t)(n0 + row) * ABCOLS) + kt_el + colel;
    gload(src, buf + i * 4096 + ((tid >> 6) << 10));
  }
}

DEVFN void g2_body(const ushort_t* __restrict__ A, const ushort_t* __restrict__ BT,
                   char* smem, int m0, int n0, int kt0, int NT,
                   ushort_t* __restrict__ outp, int tid) {
  const int l = tid & 63, l15 = l & 15, l4 = l >> 4;
  const int w = tid >> 6, wr = w >> 1, wc = w & 1;
  f32x4 acc[4][6] = {};

  g2_stage(A, BT, m0, n0, kt0, smem, tid);
  asm volatile("s_waitcnt vmcnt(0)" ::: "memory");
  __builtin_amdgcn_s_barrier();

  for (int t = 0; t < NT; ++t) {
    const char* bufA = smem + (t & 1) * G2_BUF;
    const char* bufB = bufA + 16384;
    if (t + 1 < NT) {
      g2_stage(A, BT, m0, n0, kt0 + (t + 1) * 64, smem + ((t + 1) & 1) * G2_BUF, tid);
      __builtin_amdgcn_sched_barrier(0);
    }
#pragma unroll
    for (int kk = 0; kk < 2; ++kk) {
      bf16x8 af[4], bv[6];
#pragma unroll
      for (int mi = 0; mi < 4; ++mi) {
        const int p = (wr * 64 + mi * 16 + l15) * 128 + kk * 64 + l4 * 16;
        af[mi] = *(const bf16x8*)(bufA + swz128(p));
      }
#pragma unroll
      for (int ni = 0; ni < 6; ++ni) {
        const int p = (wc * 96 + ni * 16 + l15) * 128 + kk * 64 + l4 * 16;
        bv[ni] = *(const bf16x8*)(bufB + swz128(p));
      }
#pragma unroll
      for (int mi = 0; mi < 4; ++mi)
#pragma unroll
        for (int ni = 0; ni < 6; ++ni)
          acc[mi][ni] = __builtin_amdgcn_mfma_f32_16x16x32_bf16(af[mi], bv[ni], acc[mi][ni], 0, 0, 0);
    }

    if (t + 1 < NT) {
      asm volatile("s_waitcnt vmcnt(0)" ::: "memory");
      __builtin_amdgcn_s_barrier();
    }
  }

#pragma unroll
  for (int mi = 0; mi < 4; ++mi)
#pragma unroll
    for (int ni = 0; ni < 6; ++ni)
#pragma unroll
      for (int r = 0; r < 4; ++r) {
        const int row = m0 + wr * 64 + mi * 16 + l4 * 4 + r;
        const int col = n0 + wc * 96 + ni * 16 + l15;
        outp[(size_t)row * HDIM + col] = f2bf(acc[mi][ni][r]);
      }
}

// ---------------------------------------------------------------- attention one q-tile (wave-private)
DEVFN void attn_one(const ushort_t* __restrict__ qr, const ushort_t* __restrict__ kr,
                    const ushort_t* __restrict__ vT, ushort_t* __restrict__ ab,
                    int h, int seg, int qt, ushort_t* Pw, int l15, int l4) {
  const int qrow0 = seg * SEGLEN + qt * 16;
  bf16x8 aq[2];
#pragma unroll
  for (int kk = 0; kk < 2; ++kk)
    aq[kk] = *(const bf16x8*)(qr + ((size_t)h * N_TOK + qrow0 + l15) * HD + kk * 32 + l4 * 8);

  f32x4 o[4] = {};
  float m_run[4], l_run[4];
#pragma unroll
  for (int r = 0; r < 4; ++r) { m_run[r] = -1e30f; l_run[r] = 0.f; }

  const int kbmax = qt >> 2;
  for (int kb = 0; kb <= kbmax; ++kb) {
    bf16x8 bk[4][2];
#pragma unroll
    for (int ni = 0; ni < 4; ++ni)
#pragma unroll
      for (int kk = 0; kk < 2; ++kk)
        bk[ni][kk] = *(const bf16x8*)(kr + ((size_t)h * N_TOK + seg * SEGLEN + kb * 64 + ni * 16 + l15) * HD + kk * 32 + l4 * 8);
    f32x4 s[4] = {};
#pragma unroll
    for (int ni = 0; ni < 4; ++ni)
#pragma unroll
      for (int kk = 0; kk < 2; ++kk)
        s[ni] = __builtin_amdgcn_mfma_f32_16x16x32_bf16(aq[kk], bk[ni][kk], s[ni], 0, 0, 0);

    const bool diag = (kb == kbmax);
#pragma unroll
    for (int ni = 0; ni < 4; ++ni)
#pragma unroll
      for (int r = 0; r < 4; ++r) {
        float v = s[ni][r] * 0.125f;
        if (diag) {
          const int qrow = qt * 16 + l4 * 4 + r;
          const int jcol = kb * 64 + ni * 16 + l15;
          if (jcol > qrow) v = -1e30f;
        }
        s[ni][r] = v;
      }

    float sc_[4];
#pragma unroll
    for (int r = 0; r < 4; ++r) {
      float pm = fmaxf(fmaxf(s[0][r], s[1][r]), fmaxf(s[2][r], s[3][r]));
      pm = fmaxf(pm, __shfl_xor(pm, 1));
      pm = fmaxf(pm, __shfl_xor(pm, 2));
      pm = fmaxf(pm, __shfl_xor(pm, 4));
      pm = fmaxf(pm, __shfl_xor(pm, 8));
      const float mn = fmaxf(m_run[r], pm);
      sc_[r] = __expf(m_run[r] - mn);
      m_run[r] = mn;
    }
#pragma unroll
    for (int ni = 0; ni < 4; ++ni)
#pragma unroll
      for (int r = 0; r < 4; ++r)
        s[ni][r] = __expf(s[ni][r] - m_run[r]);
#pragma unroll
    for (int r = 0; r < 4; ++r) {
      float ls = s[0][r] + s[1][r] + s[2][r] + s[3][r];
      ls += __shfl_xor(ls, 1);
      ls += __shfl_xor(ls, 2);
      ls += __shfl_xor(ls, 4);
      ls += __shfl_xor(ls, 8);
      l_run[r] = l_run[r] * sc_[r] + ls;
    }
#pragma unroll
    for (int ni = 0; ni < 4; ++ni)
#pragma unroll
      for (int r = 0; r < 4; ++r)
        o[ni][r] *= sc_[r];

#pragma unroll
    for (int ni = 0; ni < 4; ++ni)
#pragma unroll
      for (int r = 0; r < 4; ++r)
        Pw[(l4 * 4 + r) * 64 + ni * 16 + l15] = f2bf(s[ni][r]);

    bf16x8 pa[2], bv[4][2];
#pragma unroll
    for (int k2 = 0; k2 < 2; ++k2)
      pa[k2] = *(const bf16x8*)(&Pw[l15 * 64 + k2 * 32 + l4 * 8]);
#pragma unroll
    for (int ni = 0; ni < 4; ++ni)
#pragma unroll
      for (int k2 = 0; k2 < 2; ++k2)
        bv[ni][k2] = *(const bf16x8*)(vT + ((size_t)h * HD + ni * 16 + l15) * N_TOK + seg * SEGLEN + kb * 64 + k2 * 32 + l4 * 8);
#pragma unroll
    for (int ni = 0; ni < 4; ++ni)
#pragma unroll
      for (int k2 = 0; k2 < 2; ++k2)
        o[ni] = __builtin_amdgcn_mfma_f32_16x16x32_bf16(pa[k2], bv[ni][k2], o[ni], 0, 0, 0);
  }

#pragma unroll
  for (int ni = 0; ni < 4; ++ni)
#pragma unroll
    for (int r = 0; r < 4; ++r) {
      const int row = qrow0 + l4 * 4 + r;
      const int col = h * HD + ni * 16 + l15;
      ab[(size_t)row * ABCOLS + col] = f2bf(o[ni][r] / l_run[r]);
    }
}

// ---------------------------------------------------------------- fused mid: 448 blocks + extra transposes
__global__ __launch_bounds__(256, 2) void fused_mid(
    const ushort_t* __restrict__ ab, const ushort_t* __restrict__ woutT,
    ushort_t* __restrict__ cpartb,
    const ushort_t* __restrict__ qr, const ushort_t* __restrict__ kr,
    const ushort_t* __restrict__ vT, ushort_t* __restrict__ ab_out,
    const float* __restrict__ tj_src, ushort_t* __restrict__ tj_dst) {
  __shared__ __align__(16) char smem[2 * G2_BUF];     // 80 KiB
  const int b = (int)blockIdx.x;
  const int tid = threadIdx.x;
  if (b >= 448) {
    const int e = b - 448;
    transpose_tile(tj_src, tj_dst, ABCOLS, HDIM, (e / 24) * 64, (e % 24) * 32, tid, smem);
    return;
  }
  const int sel = b % 7;
  if (sel < 3) {
    const int a = (b / 7) * 3 + sel;      // 0..191
    const int h = a % NHEADS;
    const int r2 = a / NHEADS;            // 0..15
    const int seg = r2 & 7, p = r2 >> 3;  // p in {0,1}
    const int w = tid >> 6, l = tid & 63;
    const int l15 = l & 15, l4 = l >> 4;
    ushort_t* Pw = (ushort_t*)smem + w * (16 * 64);
    attn_one(qr, kr, vT, ab_out, h, seg, p * 4 + w, Pw, l15, l4);
    attn_one(qr, kr, vT, ab_out, h, seg, (3 - p) * 4 + w, Pw, l15, l4);
  } else {
    const int f = (b / 7) * 4 + (sel - 3);   // 0..255
    const int z = 1 + (f >> 6);              // ff chunks 1..4
    const int rem = f & 63;
    const int n0 = (rem & 3) * 192, m0 = (rem >> 2) * 128;
    g2_body(ab, woutT, smem, m0, n0, z * KCHUNK, 12,
            cpartb + (size_t)(z - 1) * N_TOK * HDIM, tid);
  }
}

// ---------------------------------------------------------------- gemm2 attn-column chunk (K 0..768, split in 2)
__global__ __launch_bounds__(256, 2) void gemm2_z0(
    const ushort_t* __restrict__ ab, const ushort_t* __restrict__ woutT,
    ushort_t* __restrict__ cpartb) {
  __shared__ __align__(16) char smem[2 * G2_BUF];
  const int b = (int)blockIdx.x;
  const int half = b >> 6, rem = b & 63;
  const int n0 = (rem & 3) * 192, m0 = (rem >> 2) * 128;
  g2_body(ab, woutT, smem, m0, n0, half * 384, 6,
          cpartb + (size_t)(4 + half) * N_TOK * HDIM, threadIdx.x);
}

// ----------------------------------------------------------------
extern "C" void kernel_launch(void* const* d_in, const int* in_sizes, int n_in,
                              void* d_out, int out_size, void* d_ws, size_t ws_size,
                              hipStream_t stream) {
  const int*   tokens   = (const int*)d_in[0];
  const float* ages     = (const float*)d_in[1];
  const float* time_d   = (const float*)d_in[2];
  const float* embed    = (const float*)d_in[4];
  const float* in_nw    = (const float*)d_in[5];
  const float* out_nw   = (const float*)d_in[6];
  const float* layer_nw = (const float*)d_in[7];
  const float* Win      = (const float*)d_in[8];
  const float* Wout     = (const float*)d_in[9];
  float* out = (float*)d_out;

  char* ws = (char*)d_ws;
  float*    x      = (float*)   (ws + 0);            //  6,291,456
  ushort_t* hbuf   = (ushort_t*)(ws + 6291456);      //  3,145,728
  float2*   sctab  = (float2*)  (ws + 9437184);      //  1,048,576
  ushort_t* cpartb = (ushort_t*)(ws + 10485760);     // 18,874,368 (6 bf16 slices)
  ushort_t* ab     = (ushort_t*)(ws + 29360128);     // 15,728,640
  ushort_t* qrb    = (ushort_t*)(ws + 45088768);     //  3,145,728
  ushort_t* krb    = (ushort_t*)(ws + 48234496);     //  3,145,728
  ushort_t* vTb    = (ushort_t*)(ws + 51380224);     //  3,145,728
  ushort_t* winT   = (ushort_t*)(ws + 54525952);     // 25,952,256
  ushort_t* woutT  = (ushort_t*)(ws + 80478208);     // 11,796,480

  const size_t winStride  = (size_t)TCOLS * HDIM;
  const size_t woutStride = (size_t)HDIM * ABCOLS;

  preamble<<<dim3(5216), dim3(256), 0, stream>>>(Win, winT, embed, tokens, ages,
                                                 in_nw, layer_nw, time_d, x, hbuf, sctab);

  for (int lyr = 0; lyr < 2; ++lyr) {
    if (lyr == 0) {
      gemm1f<<<dim3(528 + 4608), dim3(512), 0, stream>>>(
          hbuf, winT, sctab, ab, qrb, krb, vTb,
          Wout, woutT, Win + winStride, winT + winStride);
      fused_mid<<<dim3(448 + 1440), dim3(256), 0, stream>>>(
          ab, woutT, cpartb, qrb, krb, vTb, ab,
          Wout + woutStride, woutT + woutStride);
    } else {
      gemm1f<<<dim3(528), dim3(512), 0, stream>>>(
          hbuf, winT + winStride, sctab, ab, qrb, krb, vTb,
          nullptr, nullptr, nullptr, nullptr);
      fused_mid<<<dim3(448), dim3(256), 0, stream>>>(
          ab, woutT + woutStride, cpartb, qrb, krb, vTb, ab,
          nullptr, nullptr);
    }
    gemm2_z0<<<dim3(128), dim3(256), 0, stream>>>(ab, woutT + lyr * woutStride, cpartb);
    if (lyr == 0)
      rms_fused<<<dim3(N_TOK), dim3(256), 0, stream>>>(cpartb, x, layer_nw + HDIM, time_d,
                                                       nullptr, hbuf, 1);
    else
      rms_fused<<<dim3(N_TOK), dim3(256), 0, stream>>>(cpartb, x, out_nw, nullptr,
                                                       out, nullptr, 2);
  }
}

// Round 14
// 201.094 us; speedup vs baseline: 1.1452x; 1.1236x over previous
//
#include <hip/hip_runtime.h>
#include <math.h>

typedef unsigned short ushort_t;
typedef float f32x4 __attribute__((ext_vector_type(4)));
typedef __bf16 bf16x8 __attribute__((ext_vector_type(8)));

#define DEVFN __device__ __forceinline__

DEVFN ushort_t f2bf(float f) {
  unsigned int u = __float_as_uint(f);
  u += 0x7FFFu + ((u >> 16) & 1u);   // round-to-nearest-even
  return (ushort_t)(u >> 16);
}
DEVFN float bf2f(ushort_t u) { return __uint_as_float((unsigned int)u << 16); }

DEVFN void gload(const ushort_t* src, char* dst) {
  __builtin_amdgcn_global_load_lds(
      (const __attribute__((address_space(1))) unsigned int*)src,
      (__attribute__((address_space(3))) unsigned int*)dst, 16, 0, 0);
}

#define N_TOK  2048
#define HDIM   768
#define TCOLS  8448     // 2*I + 3*H
#define FFI    3072
#define NHEADS 12
#define HD     64
#define NSEG   8
#define SEGLEN 256
#define ABCOLS 3840     // H + I
#define NPART  6
#define KCHUNK 768

// ---------------------------------------------------------------- 64x32 transpose tile
DEVFN void transpose_tile(const float* __restrict__ in, ushort_t* __restrict__ out,
                          int R, int C, int tr, int tc, int tid, char* smem) {
  ushort_t (*tile)[66] = (ushort_t(*)[66])smem;
  const int tx = tid & 31, ty = tid >> 5;   // 32 x 8
#pragma unroll
  for (int i = 0; i < 8; ++i) {
    const int r = ty + i * 8;
    tile[tx][r] = f2bf(in[(size_t)(tr + r) * C + tc + tx]);
  }
  __syncthreads();
#pragma unroll
  for (int i = 0; i < 4; ++i) {
    const int c = ty + i * 8;
    ushort2 pk; pk.x = tile[c][2 * tx]; pk.y = tile[c][2 * tx + 1];
    *(ushort2*)(out + (size_t)(tc + c) * R + tr + 2 * tx) = pk;
  }
}

// ---------------------------------------------------------------- preamble: winT-0 transpose + rms_init
__global__ __launch_bounds__(256) void preamble(
    const float* __restrict__ Win, ushort_t* __restrict__ winT,
    const float* __restrict__ embed, const int* __restrict__ tokens,
    const float* __restrict__ ages,
    const float* __restrict__ in_nw, const float* __restrict__ layer_nw,
    const float* __restrict__ time_data,
    float* __restrict__ x, ushort_t* __restrict__ hbuf, float2* __restrict__ sctab) {
  const int tid = threadIdx.x;
  if (blockIdx.x < 3168) {
    __shared__ char tsmem[32 * 66 * 2];
    const int id = blockIdx.x;
    transpose_tile(Win, winT, HDIM, TCOLS, (id / 264) * 64, (id % 264) * 32, tid, tsmem);
    return;
  }
  const int row = blockIdx.x - 3168;
  if (tid < 32) {
    const int k = tid;
    const float e = (2.0f * (float)k) / 31.0f;
    const float t = ages[row] * expf(-e * logf(10000.0f));
    float2 cs; cs.x = cosf(t); cs.y = sinf(t);
    sctab[row * HD + 2 * k] = cs;
    sctab[row * HD + 2 * k + 1] = cs;
  }
  __shared__ float part[4];
  const float* src = embed + (size_t)tokens[row] * HDIM;
  float4 v = {0.f, 0.f, 0.f, 0.f};
  const int c0 = tid * 4;
  if (tid < 192) v = *(const float4*)(src + c0);
  float ss = v.x * v.x + v.y * v.y + v.z * v.z + v.w * v.w;
#pragma unroll
  for (int off = 1; off < 64; off <<= 1) ss += __shfl_xor(ss, off);
  if ((tid & 63) == 0) part[tid >> 6] = ss;
  __syncthreads();
  const float rs = rsqrtf((part[0] + part[1] + part[2] + part[3]) * (1.0f / HDIM) + 1e-6f);
  float4 y = {0.f, 0.f, 0.f, 0.f};
  if (tid < 192) {
    y.x = v.x * rs * in_nw[c0]; y.y = v.y * rs * in_nw[c0 + 1];
    y.z = v.z * rs * in_nw[c0 + 2]; y.w = v.w * rs * in_nw[c0 + 3];
    *(float4*)(x + (size_t)row * HDIM + c0) = y;
  }
  float ss2 = y.x * y.x + y.y * y.y + y.z * y.z + y.w * y.w;
#pragma unroll
  for (int off = 1; off < 64; off <<= 1) ss2 += __shfl_xor(ss2, off);
  __syncthreads();
  if ((tid & 63) == 0) part[tid >> 6] = ss2;
  __syncthreads();
  const float rs2 = rsqrtf((part[0] + part[1] + part[2] + part[3]) * (1.0f / HDIM) + 1e-6f);
  if (tid < 192) {
    float val[4];
#pragma unroll
    for (int j = 0; j < 4; ++j) {
      const int c = c0 + j;
      float vv = ((const float*)&y)[j] * rs2 * layer_nw[c];
      if (c >= HDIM - 4) {
        const float td = time_data[row * 2 + (c & 1)];
        vv = (c >= HDIM - 2) ? td * td : td;
      }
      val[j] = vv;
    }
    ushort4 pk;
    pk.x = f2bf(val[0]); pk.y = f2bf(val[1]); pk.z = f2bf(val[2]); pk.w = f2bf(val[3]);
    *(ushort4*)(hbuf + (size_t)row * HDIM + c0) = pk;
  }
}

// ---------------------------------------------------------------- fused reduce(6 bf16 partials) + residual + rms
__global__ __launch_bounds__(256) void rms_fused(
    const ushort_t* __restrict__ cpartb, float* __restrict__ x,
    const float* __restrict__ w, const float* __restrict__ time_data,
    float* __restrict__ out_f32, ushort_t* __restrict__ out_bf16, const int mode) {
  const int row = blockIdx.x;
  const size_t stride = (size_t)N_TOK * HDIM;
  const int tid = threadIdx.x;
  const int c0 = tid * 4;
  float4 s = {0.f, 0.f, 0.f, 0.f};
  if (tid < 192) {
    s = *(const float4*)(x + (size_t)row * HDIM + c0);
#pragma unroll
    for (int z = 0; z < NPART; ++z) {
      const ushort4 p = *(const ushort4*)(cpartb + z * stride + (size_t)row * HDIM + c0);
      s.x += bf2f(p.x); s.y += bf2f(p.y); s.z += bf2f(p.z); s.w += bf2f(p.w);
    }
    if (mode == 1) *(float4*)(x + (size_t)row * HDIM + c0) = s;
  }
  float ss = s.x * s.x + s.y * s.y + s.z * s.z + s.w * s.w;
#pragma unroll
  for (int off = 1; off < 64; off <<= 1) ss += __shfl_xor(ss, off);
  __shared__ float part[4];
  if ((tid & 63) == 0) part[tid >> 6] = ss;
  __syncthreads();
  const float rs = rsqrtf((part[0] + part[1] + part[2] + part[3]) * (1.0f / HDIM) + 1e-6f);
  if (tid < 192) {
    float val[4];
#pragma unroll
    for (int j = 0; j < 4; ++j) {
      const int c = c0 + j;
      float vv = ((const float*)&s)[j] * rs * w[c];
      if (mode == 1 && c >= HDIM - 4) {
        const float td = time_data[row * 2 + (c & 1)];
        vv = (c >= HDIM - 2) ? td * td : td;
      }
      val[j] = vv;
    }
    if (mode == 1) {
      ushort4 pk;
      pk.x = f2bf(val[0]); pk.y = f2bf(val[1]); pk.z = f2bf(val[2]); pk.w = f2bf(val[3]);
      *(ushort4*)(out_bf16 + (size_t)row * HDIM + c0) = pk;
    } else {
      float4 o; o.x = val[0]; o.y = val[1]; o.z = val[2]; o.w = val[3];
      *(float4*)(out_f32 + (size_t)row * HDIM + c0) = o;
    }
  }
}

// ---------------------------------------------------------------- GEMM1: 64x192 tile, 4 waves, acc[2][6], 4 blocks/CU
#define G1_NT 24
#define G1_ABYT 4096          // 64x32 bf16
#define G1_BUF  16384         // + 192x32 bf16 (12288)

DEVFN int swz64(int p) {
  const int g = ((p >> 6) & 3) ^ ((p >> 8) & 3);
  return p ^ (g << 4);
}
DEVFN int ffmap(int vr) {
  return (vr < 2 * FFI) ? ((((vr >> 4) & 1) * FFI) + ((vr >> 5) << 4) + (vr & 15)) : vr;
}

DEVFN void g1f_stage(const ushort_t* __restrict__ A, const ushort_t* __restrict__ BT,
                     int m0, int n0, int kt_el, char* buf, int tid) {
  {  // A: 4KB, one round
    const int q = swz64(tid * 16);
    gload(A + (size_t)(m0 + (q >> 6)) * HDIM + kt_el + ((q & 63) >> 1),
          buf + ((tid >> 6) << 10));
  }
#pragma unroll
  for (int i = 0; i < 3; ++i) {   // B: 12KB, three rounds
    const int q = swz64(i * 4096 + tid * 16);
    const int vr = n0 + (q >> 6);
    gload(BT + (size_t)ffmap(vr) * HDIM + kt_el + ((q & 63) >> 1),
          buf + G1_ABYT + i * 4096 + ((tid >> 6) << 10));
  }
}

// extra blocks (bid>=1408): e<1440 -> Wout->woutT; else -> Win lyr1 -> winT lyr1
__global__ __launch_bounds__(256, 4) void gemm1f(
    const ushort_t* __restrict__ A, const ushort_t* __restrict__ BT,
    const float2* __restrict__ sctab,
    ushort_t* __restrict__ ab, ushort_t* __restrict__ qr,
    ushort_t* __restrict__ kr, ushort_t* __restrict__ vT,
    const float* __restrict__ tj1_src, ushort_t* __restrict__ tj1_dst,
    const float* __restrict__ tj2_src, ushort_t* __restrict__ tj2_dst) {
  __shared__ __align__(16) char smem[2 * G1_BUF];     // 32 KiB
  const int tid = threadIdx.x;
  const int bid = (int)blockIdx.x;
  if (bid >= 1408) {
    int e = bid - 1408;
    if (e < 1440)
      transpose_tile(tj1_src, tj1_dst, ABCOLS, HDIM, (e / 24) * 64, (e % 24) * 32, tid, smem);
    else {
      e -= 1440;
      transpose_tile(tj2_src, tj2_dst, HDIM, TCOLS, (e / 264) * 64, (e % 264) * 32, tid, smem);
    }
    return;
  }
  const int l = tid & 63, l15 = l & 15, l4 = l >> 4;
  const int wid = tid >> 6, wr = wid >> 1, wc = wid & 1;   // 2x2 waves, 32x96 each
  const int wg = (bid & 7) * 176 + (bid >> 3);             // XCD-contiguous
  const int nt = wg >> 5, mt = wg & 31;                    // 44 N-tiles x 32 M-tiles
  const int m0 = mt * 64, n0 = nt * 192;

  f32x4 acc[2][6] = {};

  g1f_stage(A, BT, m0, n0, 0, smem, tid);
  asm volatile("s_waitcnt vmcnt(0)" ::: "memory");
  __builtin_amdgcn_s_barrier();

  for (int t = 0; t < G1_NT; ++t) {
    const char* bufA = smem + (t & 1) * G1_BUF;
    const char* bufB = bufA + G1_ABYT;
    if (t + 1 < G1_NT) {
      g1f_stage(A, BT, m0, n0, (t + 1) * 32, smem + ((t + 1) & 1) * G1_BUF, tid);
      __builtin_amdgcn_sched_barrier(0);
    }
    bf16x8 a2[2], b6[6];
#pragma unroll
    for (int m = 0; m < 2; ++m) {
      const int p = (wr * 32 + m * 16 + l15) * 64 + l4 * 16;
      a2[m] = *(const bf16x8*)(bufA + swz64(p));
    }
#pragma unroll
    for (int n = 0; n < 6; ++n) {
      const int p = (wc * 96 + n * 16 + l15) * 64 + l4 * 16;
      b6[n] = *(const bf16x8*)(bufB + swz64(p));
    }
#pragma unroll
    for (int m = 0; m < 2; ++m)
#pragma unroll
      for (int n = 0; n < 6; ++n)
        acc[m][n] = __builtin_amdgcn_mfma_f32_16x16x32_bf16(a2[m], b6[n], acc[m][n], 0, 0, 0);

    if (t + 1 < G1_NT) {
      asm volatile("s_waitcnt vmcnt(0)" ::: "memory");
      __builtin_amdgcn_s_barrier();
    }
  }

  if (nt < 32) {
#pragma unroll
    for (int m = 0; m < 2; ++m)
#pragma unroll
      for (int np = 0; np < 3; ++np) {
        const int colj = (nt * 6 + wc * 3 + np) * 16 + l15;
#pragma unroll
        for (int r = 0; r < 4; ++r) {
          const float x1 = acc[m][2 * np][r], x2 = acc[m][2 * np + 1][r];
          const float sv = x1 / (1.f + __expf(-x1)) * x2;
          const int row = m0 + wr * 32 + m * 16 + l4 * 4 + r;
          ab[(size_t)row * ABCOLS + HDIM + colj] = f2bf(sv);
        }
      }
  } else {
#pragma unroll
    for (int n = 0; n < 6; ++n) {
      const int gcol = (nt - 32) * 192 + wc * 96 + n * 16;
      const int g = gcol >> 6;
      const int typ = g / NHEADS, h = g - typ * NHEADS;
      const int d = (gcol & 63) + l15;
      if (typ == 2) {
#pragma unroll
        for (int m = 0; m < 2; ++m) {
          ushort4 pk;
          pk.x = f2bf(acc[m][n][0]); pk.y = f2bf(acc[m][n][1]);
          pk.z = f2bf(acc[m][n][2]); pk.w = f2bf(acc[m][n][3]);
          const int row0 = m0 + wr * 32 + m * 16 + l4 * 4;
          *(ushort4*)(vT + ((size_t)h * HD + d) * N_TOK + row0) = pk;
        }
      } else {
        ushort_t* dst = (typ == 0) ? qr : kr;
        const float sgn = (l15 & 1) ? 1.f : -1.f;
#pragma unroll
        for (int m = 0; m < 2; ++m)
#pragma unroll
          for (int r = 0; r < 4; ++r) {
            const float val = acc[m][n][r];
            const float partner = __shfl_xor(val, 1);
            const int row = m0 + wr * 32 + m * 16 + l4 * 4 + r;
            const float2 cs = sctab[row * HD + d];
            dst[((size_t)h * N_TOK + row) * HD + d] = f2bf(val * cs.x + sgn * partner * cs.y);
          }
      }
    }
  }
}

// ---------------------------------------------------------------- GEMM2 body: 128x192, BK=64, single-barrier 2-phase
#define G2_BUF 40960          // A 16KB + B 24KB

DEVFN int swz128(int p) { return p ^ (((p >> 7) & 7) << 4); }

DEVFN void g2_stage(const ushort_t* __restrict__ A, const ushort_t* __restrict__ BT,
                    int m0, int n0, int kt_el, char* buf, int tid) {
#pragma unroll
  for (int i = 0; i < 10; ++i) {
    const int p = i * 4096 + tid * 16;
    const bool isA = p < 16384;
    const int q = swz128(isA ? p : p - 16384);
    const int row = q >> 7, colel = (q & 127) >> 1;
    const ushort_t* src = (isA ? A + (size_t)(m0 + row) * ABCOLS
                               : BT + (size_t)(n0 + row) * ABCOLS) + kt_el + colel;
    gload(src, buf + i * 4096 + ((tid >> 6) << 10));
  }
}

DEVFN void g2_body(const ushort_t* __restrict__ A, const ushort_t* __restrict__ BT,
                   char* smem, int m0, int n0, int kt0, int NT,
                   ushort_t* __restrict__ outp, int tid) {
  const int l = tid & 63, l15 = l & 15, l4 = l >> 4;
  const int w = tid >> 6, wr = w >> 1, wc = w & 1;
  f32x4 acc[4][6] = {};

  g2_stage(A, BT, m0, n0, kt0, smem, tid);
  asm volatile("s_waitcnt vmcnt(0)" ::: "memory");
  __builtin_amdgcn_s_barrier();

  for (int t = 0; t < NT; ++t) {
    const char* bufA = smem + (t & 1) * G2_BUF;
    const char* bufB = bufA + 16384;
    if (t + 1 < NT) {
      g2_stage(A, BT, m0, n0, kt0 + (t + 1) * 64, smem + ((t + 1) & 1) * G2_BUF, tid);
      __builtin_amdgcn_sched_barrier(0);
    }
#pragma unroll
    for (int kk = 0; kk < 2; ++kk) {
      bf16x8 af[4], bv[6];
#pragma unroll
      for (int mi = 0; mi < 4; ++mi) {
        const int p = (wr * 64 + mi * 16 + l15) * 128 + kk * 64 + l4 * 16;
        af[mi] = *(const bf16x8*)(bufA + swz128(p));
      }
#pragma unroll
      for (int ni = 0; ni < 6; ++ni) {
        const int p = (wc * 96 + ni * 16 + l15) * 128 + kk * 64 + l4 * 16;
        bv[ni] = *(const bf16x8*)(bufB + swz128(p));
      }
#pragma unroll
      for (int mi = 0; mi < 4; ++mi)
#pragma unroll
        for (int ni = 0; ni < 6; ++ni)
          acc[mi][ni] = __builtin_amdgcn_mfma_f32_16x16x32_bf16(af[mi], bv[ni], acc[mi][ni], 0, 0, 0);
    }

    if (t + 1 < NT) {
      asm volatile("s_waitcnt vmcnt(0)" ::: "memory");
      __builtin_amdgcn_s_barrier();
    }
  }

#pragma unroll
  for (int mi = 0; mi < 4; ++mi)
#pragma unroll
    for (int ni = 0; ni < 6; ++ni)
#pragma unroll
      for (int r = 0; r < 4; ++r) {
        const int row = m0 + wr * 64 + mi * 16 + l4 * 4 + r;
        const int col = n0 + wc * 96 + ni * 16 + l15;
        outp[(size_t)row * HDIM + col] = f2bf(acc[mi][ni][r]);
      }
}

// ---------------------------------------------------------------- attention one q-tile (wave-private)
DEVFN void attn_one(const ushort_t* __restrict__ qr, const ushort_t* __restrict__ kr,
                    const ushort_t* __restrict__ vT, ushort_t* __restrict__ ab,
                    int h, int seg, int qt, ushort_t* Pw, int l15, int l4) {
  const int qrow0 = seg * SEGLEN + qt * 16;
  bf16x8 aq[2];
#pragma unroll
  for (int kk = 0; kk < 2; ++kk)
    aq[kk] = *(const bf16x8*)(qr + ((size_t)h * N_TOK + qrow0 + l15) * HD + kk * 32 + l4 * 8);

  f32x4 o[4] = {};
  float m_run[4], l_run[4];
#pragma unroll
  for (int r = 0; r < 4; ++r) { m_run[r] = -1e30f; l_run[r] = 0.f; }

  const int kbmax = qt >> 2;
  for (int kb = 0; kb <= kbmax; ++kb) {
    bf16x8 bk[4][2];
#pragma unroll
    for (int ni = 0; ni < 4; ++ni)
#pragma unroll
      for (int kk = 0; kk < 2; ++kk)
        bk[ni][kk] = *(const bf16x8*)(kr + ((size_t)h * N_TOK + seg * SEGLEN + kb * 64 + ni * 16 + l15) * HD + kk * 32 + l4 * 8);
    f32x4 s[4] = {};
#pragma unroll
    for (int ni = 0; ni < 4; ++ni)
#pragma unroll
      for (int kk = 0; kk < 2; ++kk)
        s[ni] = __builtin_amdgcn_mfma_f32_16x16x32_bf16(aq[kk], bk[ni][kk], s[ni], 0, 0, 0);

    const bool diag = (kb == kbmax);
#pragma unroll
    for (int ni = 0; ni < 4; ++ni)
#pragma unroll
      for (int r = 0; r < 4; ++r) {
        float v = s[ni][r] * 0.125f;
        if (diag) {
          const int qrow = qt * 16 + l4 * 4 + r;
          const int jcol = kb * 64 + ni * 16 + l15;
          if (jcol > qrow) v = -1e30f;
        }
        s[ni][r] = v;
      }

    float sc_[4];
#pragma unroll
    for (int r = 0; r < 4; ++r) {
      float pm = fmaxf(fmaxf(s[0][r], s[1][r]), fmaxf(s[2][r], s[3][r]));
      pm = fmaxf(pm, __shfl_xor(pm, 1));
      pm = fmaxf(pm, __shfl_xor(pm, 2));
      pm = fmaxf(pm, __shfl_xor(pm, 4));
      pm = fmaxf(pm, __shfl_xor(pm, 8));
      const float mn = fmaxf(m_run[r], pm);
      sc_[r] = __expf(m_run[r] - mn);
      m_run[r] = mn;
    }
#pragma unroll
    for (int ni = 0; ni < 4; ++ni)
#pragma unroll
      for (int r = 0; r < 4; ++r)
        s[ni][r] = __expf(s[ni][r] - m_run[r]);
#pragma unroll
    for (int r = 0; r < 4; ++r) {
      float ls = s[0][r] + s[1][r] + s[2][r] + s[3][r];
      ls += __shfl_xor(ls, 1);
      ls += __shfl_xor(ls, 2);
      ls += __shfl_xor(ls, 4);
      ls += __shfl_xor(ls, 8);
      l_run[r] = l_run[r] * sc_[r] + ls;
    }
#pragma unroll
    for (int ni = 0; ni < 4; ++ni)
#pragma unroll
      for (int r = 0; r < 4; ++r)
        o[ni][r] *= sc_[r];

#pragma unroll
    for (int ni = 0; ni < 4; ++ni)
#pragma unroll
      for (int r = 0; r < 4; ++r)
        Pw[(l4 * 4 + r) * 64 + ni * 16 + l15] = f2bf(s[ni][r]);

    bf16x8 pa[2], bv[4][2];
#pragma unroll
    for (int k2 = 0; k2 < 2; ++k2)
      pa[k2] = *(const bf16x8*)(&Pw[l15 * 64 + k2 * 32 + l4 * 8]);
#pragma unroll
    for (int ni = 0; ni < 4; ++ni)
#pragma unroll
      for (int k2 = 0; k2 < 2; ++k2)
        bv[ni][k2] = *(const bf16x8*)(vT + ((size_t)h * HD + ni * 16 + l15) * N_TOK + seg * SEGLEN + kb * 64 + k2 * 32 + l4 * 8);
#pragma unroll
    for (int ni = 0; ni < 4; ++ni)
#pragma unroll
      for (int k2 = 0; k2 < 2; ++k2)
        o[ni] = __builtin_amdgcn_mfma_f32_16x16x32_bf16(pa[k2], bv[ni][k2], o[ni], 0, 0, 0);
  }

#pragma unroll
  for (int ni = 0; ni < 4; ++ni)
#pragma unroll
    for (int r = 0; r < 4; ++r) {
      const int row = qrow0 + l4 * 4 + r;
      const int col = h * HD + ni * 16 + l15;
      ab[(size_t)row * ABCOLS + col] = f2bf(o[ni][r] / l_run[r]);
    }
}

// ---------------------------------------------------------------- fused mid: 448 blocks + extra transposes
__global__ __launch_bounds__(256, 2) void fused_mid(
    const ushort_t* __restrict__ ab, const ushort_t* __restrict__ woutT,
    ushort_t* __restrict__ cpartb,
    const ushort_t* __restrict__ qr, const ushort_t* __restrict__ kr,
    const ushort_t* __restrict__ vT, ushort_t* __restrict__ ab_out,
    const float* __restrict__ tj_src, ushort_t* __restrict__ tj_dst) {
  __shared__ __align__(16) char smem[2 * G2_BUF];     // 80 KiB
  const int b = (int)blockIdx.x;
  const int tid = threadIdx.x;
  if (b >= 448) {
    const int e = b - 448;
    transpose_tile(tj_src, tj_dst, ABCOLS, HDIM, (e / 24) * 64, (e % 24) * 32, tid, smem);
    return;
  }
  const int sel = b % 7;
  if (sel < 3) {
    const int a = (b / 7) * 3 + sel;      // 0..191
    const int h = a % NHEADS;
    const int r2 = a / NHEADS;            // 0..15
    const int seg = r2 & 7, p = r2 >> 3;  // p in {0,1}
    const int w = tid >> 6, l = tid & 63;
    const int l15 = l & 15, l4 = l >> 4;
    ushort_t* Pw = (ushort_t*)smem + w * (16 * 64);
    attn_one(qr, kr, vT, ab_out, h, seg, p * 4 + w, Pw, l15, l4);
    attn_one(qr, kr, vT, ab_out, h, seg, (3 - p) * 4 + w, Pw, l15, l4);
  } else {
    const int f = (b / 7) * 4 + (sel - 3);   // 0..255
    const int z = 1 + (f >> 6);              // ff chunks 1..4
    const int rem = f & 63;
    const int n0 = (rem & 3) * 192, m0 = (rem >> 2) * 128;
    g2_body(ab, woutT, smem, m0, n0, z * KCHUNK, 12,
            cpartb + (size_t)(z - 1) * N_TOK * HDIM, tid);
  }
}

// ---------------------------------------------------------------- gemm2 attn-column chunk (K 0..768, split in 2)
__global__ __launch_bounds__(256, 2) void gemm2_z0(
    const ushort_t* __restrict__ ab, const ushort_t* __restrict__ woutT,
    ushort_t* __restrict__ cpartb) {
  __shared__ __align__(16) char smem[2 * G2_BUF];
  const int b = (int)blockIdx.x;
  const int half = b >> 6, rem = b & 63;
  const int n0 = (rem & 3) * 192, m0 = (rem >> 2) * 128;
  g2_body(ab, woutT, smem, m0, n0, half * 384, 6,
          cpartb + (size_t)(4 + half) * N_TOK * HDIM, threadIdx.x);
}

// ----------------------------------------------------------------
extern "C" void kernel_launch(void* const* d_in, const int* in_sizes, int n_in,
                              void* d_out, int out_size, void* d_ws, size_t ws_size,
                              hipStream_t stream) {
  const int*   tokens   = (const int*)d_in[0];
  const float* ages     = (const float*)d_in[1];
  const float* time_d   = (const float*)d_in[2];
  const float* embed    = (const float*)d_in[4];
  const float* in_nw    = (const float*)d_in[5];
  const float* out_nw   = (const float*)d_in[6];
  const float* layer_nw = (const float*)d_in[7];
  const float* Win      = (const float*)d_in[8];
  const float* Wout     = (const float*)d_in[9];
  float* out = (float*)d_out;

  char* ws = (char*)d_ws;
  float*    x      = (float*)   (ws + 0);            //  6,291,456
  ushort_t* hbuf   = (ushort_t*)(ws + 6291456);      //  3,145,728
  float2*   sctab  = (float2*)  (ws + 9437184);      //  1,048,576
  ushort_t* cpartb = (ushort_t*)(ws + 10485760);     // 18,874,368 (6 bf16 slices)
  ushort_t* ab     = (ushort_t*)(ws + 29360128);     // 15,728,640
  ushort_t* qrb    = (ushort_t*)(ws + 45088768);     //  3,145,728
  ushort_t* krb    = (ushort_t*)(ws + 48234496);     //  3,145,728
  ushort_t* vTb    = (ushort_t*)(ws + 51380224);     //  3,145,728
  ushort_t* winT   = (ushort_t*)(ws + 54525952);     // 25,952,256
  ushort_t* woutT  = (ushort_t*)(ws + 80478208);     // 11,796,480

  const size_t winStride  = (size_t)TCOLS * HDIM;
  const size_t woutStride = (size_t)HDIM * ABCOLS;

  preamble<<<dim3(5216), dim3(256), 0, stream>>>(Win, winT, embed, tokens, ages,
                                                 in_nw, layer_nw, time_d, x, hbuf, sctab);

  for (int lyr = 0; lyr < 2; ++lyr) {
    if (lyr == 0) {
      gemm1f<<<dim3(1408 + 4608), dim3(256), 0, stream>>>(
          hbuf, winT, sctab, ab, qrb, krb, vTb,
          Wout, woutT, Win + winStride, winT + winStride);
      fused_mid<<<dim3(448 + 1440), dim3(256), 0, stream>>>(
          ab, woutT, cpartb, qrb, krb, vTb, ab,
          Wout + woutStride, woutT + woutStride);
    } else {
      gemm1f<<<dim3(1408), dim3(256), 0, stream>>>(
          hbuf, winT + winStride, sctab, ab, qrb, krb, vTb,
          nullptr, nullptr, nullptr, nullptr);
      fused_mid<<<dim3(448), dim3(256), 0, stream>>>(
          ab, woutT + woutStride, cpartb, qrb, krb, vTb, ab,
          nullptr, nullptr);
    }
    gemm2_z0<<<dim3(128), dim3(256), 0, stream>>>(ab, woutT + lyr * woutStride, cpartb);
    if (lyr == 0)
      rms_fused<<<dim3(N_TOK), dim3(256), 0, stream>>>(cpartb, x, layer_nw + HDIM, time_d,
                                                       nullptr, hbuf, 1);
    else
      rms_fused<<<dim3(N_TOK), dim3(256), 0, stream>>>(cpartb, x, out_nw, nullptr,
                                                       out, nullptr, 2);
  }
}

// Round 15
// 185.441 us; speedup vs baseline: 1.2419x; 1.0844x over previous
//
#include <hip/hip_runtime.h>
#include <math.h>

typedef unsigned short ushort_t;
typedef float f32x4 __attribute__((ext_vector_type(4)));
typedef __bf16 bf16x8 __attribute__((ext_vector_type(8)));

#define DEVFN __device__ __forceinline__

DEVFN ushort_t f2bf(float f) {
  unsigned int u = __float_as_uint(f);
  u += 0x7FFFu + ((u >> 16) & 1u);   // round-to-nearest-even
  return (ushort_t)(u >> 16);
}
DEVFN float bf2f(ushort_t u) { return __uint_as_float((unsigned int)u << 16); }

DEVFN void gload(const ushort_t* src, char* dst) {
  __builtin_amdgcn_global_load_lds(
      (const __attribute__((address_space(1))) unsigned int*)src,
      (__attribute__((address_space(3))) unsigned int*)dst, 16, 0, 0);
}

#define N_TOK  2048
#define HDIM   768
#define TCOLS  8448     // 2*I + 3*H
#define FFI    3072
#define NHEADS 12
#define HD     64
#define NSEG   8
#define SEGLEN 256
#define ABCOLS 3840     // H + I
#define NPART  6
#define KCHUNK 768

// ---------------------------------------------------------------- 64x32 transpose tile
DEVFN void transpose_tile(const float* __restrict__ in, ushort_t* __restrict__ out,
                          int R, int C, int tr, int tc, int tid, char* smem) {
  ushort_t (*tile)[66] = (ushort_t(*)[66])smem;
  const int tx = tid & 31, ty = tid >> 5;   // 32 x 8
#pragma unroll
  for (int i = 0; i < 8; ++i) {
    const int r = ty + i * 8;
    tile[tx][r] = f2bf(in[(size_t)(tr + r) * C + tc + tx]);
  }
  __syncthreads();
#pragma unroll
  for (int i = 0; i < 4; ++i) {
    const int c = ty + i * 8;
    ushort2 pk; pk.x = tile[c][2 * tx]; pk.y = tile[c][2 * tx + 1];
    *(ushort2*)(out + (size_t)(tc + c) * R + tr + 2 * tx) = pk;
  }
}

// ---------------------------------------------------------------- preamble: winT-0 transpose + rms_init
__global__ __launch_bounds__(256) void preamble(
    const float* __restrict__ Win, ushort_t* __restrict__ winT,
    const float* __restrict__ embed, const int* __restrict__ tokens,
    const float* __restrict__ ages,
    const float* __restrict__ in_nw, const float* __restrict__ layer_nw,
    const float* __restrict__ time_data,
    float* __restrict__ x, ushort_t* __restrict__ hbuf, float2* __restrict__ sctab) {
  const int tid = threadIdx.x;
  if (blockIdx.x < 3168) {
    __shared__ char tsmem[32 * 66 * 2];
    const int id = blockIdx.x;
    transpose_tile(Win, winT, HDIM, TCOLS, (id / 264) * 64, (id % 264) * 32, tid, tsmem);
    return;
  }
  const int row = blockIdx.x - 3168;
  if (tid < 32) {
    const int k = tid;
    const float e = (2.0f * (float)k) / 31.0f;
    const float t = ages[row] * expf(-e * logf(10000.0f));
    float2 cs; cs.x = cosf(t); cs.y = sinf(t);
    sctab[row * HD + 2 * k] = cs;
    sctab[row * HD + 2 * k + 1] = cs;
  }
  __shared__ float part[4];
  const float* src = embed + (size_t)tokens[row] * HDIM;
  float4 v = {0.f, 0.f, 0.f, 0.f};
  const int c0 = tid * 4;
  if (tid < 192) v = *(const float4*)(src + c0);
  float ss = v.x * v.x + v.y * v.y + v.z * v.z + v.w * v.w;
#pragma unroll
  for (int off = 1; off < 64; off <<= 1) ss += __shfl_xor(ss, off);
  if ((tid & 63) == 0) part[tid >> 6] = ss;
  __syncthreads();
  const float rs = rsqrtf((part[0] + part[1] + part[2] + part[3]) * (1.0f / HDIM) + 1e-6f);
  float4 y = {0.f, 0.f, 0.f, 0.f};
  if (tid < 192) {
    y.x = v.x * rs * in_nw[c0]; y.y = v.y * rs * in_nw[c0 + 1];
    y.z = v.z * rs * in_nw[c0 + 2]; y.w = v.w * rs * in_nw[c0 + 3];
    *(float4*)(x + (size_t)row * HDIM + c0) = y;
  }
  float ss2 = y.x * y.x + y.y * y.y + y.z * y.z + y.w * y.w;
#pragma unroll
  for (int off = 1; off < 64; off <<= 1) ss2 += __shfl_xor(ss2, off);
  __syncthreads();
  if ((tid & 63) == 0) part[tid >> 6] = ss2;
  __syncthreads();
  const float rs2 = rsqrtf((part[0] + part[1] + part[2] + part[3]) * (1.0f / HDIM) + 1e-6f);
  if (tid < 192) {
    float val[4];
#pragma unroll
    for (int j = 0; j < 4; ++j) {
      const int c = c0 + j;
      float vv = ((const float*)&y)[j] * rs2 * layer_nw[c];
      if (c >= HDIM - 4) {
        const float td = time_data[row * 2 + (c & 1)];
        vv = (c >= HDIM - 2) ? td * td : td;
      }
      val[j] = vv;
    }
    ushort4 pk;
    pk.x = f2bf(val[0]); pk.y = f2bf(val[1]); pk.z = f2bf(val[2]); pk.w = f2bf(val[3]);
    *(ushort4*)(hbuf + (size_t)row * HDIM + c0) = pk;
  }
}

// ---------------------------------------------------------------- fused reduce(6 bf16 partials) + residual + rms
__global__ __launch_bounds__(256) void rms_fused(
    const ushort_t* __restrict__ cpartb, float* __restrict__ x,
    const float* __restrict__ w, const float* __restrict__ time_data,
    float* __restrict__ out_f32, ushort_t* __restrict__ out_bf16, const int mode) {
  const int row = blockIdx.x;
  const size_t stride = (size_t)N_TOK * HDIM;
  const int tid = threadIdx.x;
  const int c0 = tid * 4;
  float4 s = {0.f, 0.f, 0.f, 0.f};
  if (tid < 192) {
    s = *(const float4*)(x + (size_t)row * HDIM + c0);
#pragma unroll
    for (int z = 0; z < NPART; ++z) {
      const ushort4 p = *(const ushort4*)(cpartb + z * stride + (size_t)row * HDIM + c0);
      s.x += bf2f(p.x); s.y += bf2f(p.y); s.z += bf2f(p.z); s.w += bf2f(p.w);
    }
    if (mode == 1) *(float4*)(x + (size_t)row * HDIM + c0) = s;
  }
  float ss = s.x * s.x + s.y * s.y + s.z * s.z + s.w * s.w;
#pragma unroll
  for (int off = 1; off < 64; off <<= 1) ss += __shfl_xor(ss, off);
  __shared__ float part[4];
  if ((tid & 63) == 0) part[tid >> 6] = ss;
  __syncthreads();
  const float rs = rsqrtf((part[0] + part[1] + part[2] + part[3]) * (1.0f / HDIM) + 1e-6f);
  if (tid < 192) {
    float val[4];
#pragma unroll
    for (int j = 0; j < 4; ++j) {
      const int c = c0 + j;
      float vv = ((const float*)&s)[j] * rs * w[c];
      if (mode == 1 && c >= HDIM - 4) {
        const float td = time_data[row * 2 + (c & 1)];
        vv = (c >= HDIM - 2) ? td * td : td;
      }
      val[j] = vv;
    }
    if (mode == 1) {
      ushort4 pk;
      pk.x = f2bf(val[0]); pk.y = f2bf(val[1]); pk.z = f2bf(val[2]); pk.w = f2bf(val[3]);
      *(ushort4*)(out_bf16 + (size_t)row * HDIM + c0) = pk;
    } else {
      float4 o; o.x = val[0]; o.y = val[1]; o.z = val[2]; o.w = val[3];
      *(float4*)(out_f32 + (size_t)row * HDIM + c0) = o;
    }
  }
}

// ---------------------------------------------------------------- GEMM1: 128x192, 4 waves, 3-buffer counted-vmcnt pipeline
#define G1_NT 24
#define G1_ABYT 8192
#define G1_BUF  20480

DEVFN int swz64(int p) {
  const int g = ((p >> 6) & 3) ^ ((p >> 8) & 3);
  return p ^ (g << 4);
}
DEVFN int ffmap(int vr) {
  return (vr < 2 * FFI) ? ((((vr >> 4) & 1) * FFI) + ((vr >> 5) << 4) + (vr & 15)) : vr;
}

DEVFN void g1f_stage(const ushort_t* __restrict__ A, const ushort_t* __restrict__ BT,
                     int m0, int n0, int kt_el, char* buf, int tid) {
#pragma unroll
  for (int i = 0; i < 2; ++i) {
    const int q = swz64(i * 4096 + tid * 16);
    gload(A + (size_t)(m0 + (q >> 6)) * HDIM + kt_el + ((q & 63) >> 1),
          buf + i * 4096 + ((tid >> 6) << 10));
  }
#pragma unroll
  for (int i = 0; i < 3; ++i) {
    const int q = swz64(i * 4096 + tid * 16);
    const int vr = n0 + (q >> 6);
    gload(BT + (size_t)ffmap(vr) * HDIM + kt_el + ((q & 63) >> 1),
          buf + G1_ABYT + i * 4096 + ((tid >> 6) << 10));
  }
}

// extra blocks (bid>=704): e<1440 -> Wout->woutT; else -> Win lyr1 -> winT lyr1
__global__ __launch_bounds__(256, 2) void gemm1f(
    const ushort_t* __restrict__ A, const ushort_t* __restrict__ BT,
    const float2* __restrict__ sctab,
    ushort_t* __restrict__ ab, ushort_t* __restrict__ qr,
    ushort_t* __restrict__ kr, ushort_t* __restrict__ vT,
    const float* __restrict__ tj1_src, ushort_t* __restrict__ tj1_dst,
    const float* __restrict__ tj2_src, ushort_t* __restrict__ tj2_dst) {
  __shared__ __align__(16) char smem[3 * G1_BUF];     // 60 KiB, triple-buffered
  const int tid = threadIdx.x;
  const int bid = (int)blockIdx.x;
  if (bid >= 704) {
    int e = bid - 704;
    if (e < 1440)
      transpose_tile(tj1_src, tj1_dst, ABCOLS, HDIM, (e / 24) * 64, (e % 24) * 32, tid, smem);
    else {
      e -= 1440;
      transpose_tile(tj2_src, tj2_dst, HDIM, TCOLS, (e / 264) * 64, (e % 264) * 32, tid, smem);
    }
    return;
  }
  const int l = tid & 63, l15 = l & 15, l4 = l >> 4;
  const int wid = tid >> 6, wr = wid >> 1, wc = wid & 1;
  const int wg = (bid & 7) * 88 + (bid >> 3);
  const int nt = wg >> 4, mt = wg & 15;
  const int m0 = mt * 128, n0 = nt * 192;

  f32x4 acc[4][6] = {};

  // prologue: stage tiles 0,1 into buffers 0,1 (no wait — pipeline fills)
  g1f_stage(A, BT, m0, n0, 0,  smem, tid);
  g1f_stage(A, BT, m0, n0, 32, smem + G1_BUF, tid);

  for (int t = 0; t < G1_NT; ++t) {
    // wait: tile t landed (its 5 loads are older than the newest 5 = stage(t+1))
    if (t < G1_NT - 1) asm volatile("s_waitcnt vmcnt(5)" ::: "memory");
    else               asm volatile("s_waitcnt vmcnt(0)" ::: "memory");
    __builtin_amdgcn_s_barrier();          // collective: ALL waves' tile-t loads done

    const char* bufA = smem + (t % 3) * G1_BUF;
    const char* bufB = bufA + G1_ABYT;
    bf16x8 a4[4], b6[6];
#pragma unroll
    for (int m = 0; m < 4; ++m) {
      const int p = (wr * 64 + m * 16 + l15) * 64 + l4 * 16;
      a4[m] = *(const bf16x8*)(bufA + swz64(p));
    }
#pragma unroll
    for (int n = 0; n < 6; ++n) {
      const int p = (wc * 96 + n * 16 + l15) * 64 + l4 * 16;
      b6[n] = *(const bf16x8*)(bufB + swz64(p));
    }
    // issue stage(t+2) AFTER our reads of buf[(t+2)%3]'s alias are long past (barrier t closed iter t-1)
    if (t + 2 < G1_NT)
      g1f_stage(A, BT, m0, n0, (t + 2) * 32, smem + ((t + 2) % 3) * G1_BUF, tid);
#pragma unroll
    for (int m = 0; m < 4; ++m)
#pragma unroll
      for (int n = 0; n < 6; ++n)
        acc[m][n] = __builtin_amdgcn_mfma_f32_16x16x32_bf16(a4[m], b6[n], acc[m][n], 0, 0, 0);
  }

  if (nt < 32) {
#pragma unroll
    for (int m = 0; m < 4; ++m)
#pragma unroll
      for (int np = 0; np < 3; ++np) {
        const int colj = (nt * 6 + wc * 3 + np) * 16 + l15;
#pragma unroll
        for (int r = 0; r < 4; ++r) {
          const float x1 = acc[m][2 * np][r], x2 = acc[m][2 * np + 1][r];
          const float sv = x1 / (1.f + __expf(-x1)) * x2;
          const int row = m0 + wr * 64 + m * 16 + l4 * 4 + r;
          ab[(size_t)row * ABCOLS + HDIM + colj] = f2bf(sv);
        }
      }
  } else {
#pragma unroll
    for (int n = 0; n < 6; ++n) {
      const int gcol = (nt - 32) * 192 + wc * 96 + n * 16;
      const int g = gcol >> 6;
      const int typ = g / NHEADS, h = g - typ * NHEADS;
      const int d = (gcol & 63) + l15;
      if (typ == 2) {
#pragma unroll
        for (int m = 0; m < 4; ++m) {
          ushort4 pk;
          pk.x = f2bf(acc[m][n][0]); pk.y = f2bf(acc[m][n][1]);
          pk.z = f2bf(acc[m][n][2]); pk.w = f2bf(acc[m][n][3]);
          const int row0 = m0 + wr * 64 + m * 16 + l4 * 4;
          *(ushort4*)(vT + ((size_t)h * HD + d) * N_TOK + row0) = pk;
        }
      } else {
        ushort_t* dst = (typ == 0) ? qr : kr;
        const float sgn = (l15 & 1) ? 1.f : -1.f;
#pragma unroll
        for (int m = 0; m < 4; ++m)
#pragma unroll
          for (int r = 0; r < 4; ++r) {
            const float val = acc[m][n][r];
            const float partner = __shfl_xor(val, 1);
            const int row = m0 + wr * 64 + m * 16 + l4 * 4 + r;
            const float2 cs = sctab[row * HD + d];
            dst[((size_t)h * N_TOK + row) * HD + d] = f2bf(val * cs.x + sgn * partner * cs.y);
          }
      }
    }
  }
}

// ---------------------------------------------------------------- GEMM2 body: 128x192, BK=64, single-barrier 2-phase
#define G2_BUF 40960          // A 16KB + B 24KB

DEVFN int swz128(int p) { return p ^ (((p >> 7) & 7) << 4); }

DEVFN void g2_stage(const ushort_t* __restrict__ A, const ushort_t* __restrict__ BT,
                    int m0, int n0, int kt_el, char* buf, int tid) {
#pragma unroll
  for (int i = 0; i < 10; ++i) {
    const int p = i * 4096 + tid * 16;
    const bool isA = p < 16384;
    const int q = swz128(isA ? p : p - 16384);
    const int row = q >> 7, colel = (q & 127) >> 1;
    const ushort_t* src = (isA ? A + (size_t)(m0 + row) * ABCOLS
                               : BT + (size_t)(n0 + row) * ABCOLS) + kt_el + colel;
    gload(src, buf + i * 4096 + ((tid >> 6) << 10));
  }
}

DEVFN void g2_body(const ushort_t* __restrict__ A, const ushort_t* __restrict__ BT,
                   char* smem, int m0, int n0, int kt0, int NT,
                   ushort_t* __restrict__ outp, int tid) {
  const int l = tid & 63, l15 = l & 15, l4 = l >> 4;
  const int w = tid >> 6, wr = w >> 1, wc = w & 1;
  f32x4 acc[4][6] = {};

  g2_stage(A, BT, m0, n0, kt0, smem, tid);
  asm volatile("s_waitcnt vmcnt(0)" ::: "memory");
  __builtin_amdgcn_s_barrier();

  for (int t = 0; t < NT; ++t) {
    const char* bufA = smem + (t & 1) * G2_BUF;
    const char* bufB = bufA + 16384;
    if (t + 1 < NT) {
      g2_stage(A, BT, m0, n0, kt0 + (t + 1) * 64, smem + ((t + 1) & 1) * G2_BUF, tid);
      __builtin_amdgcn_sched_barrier(0);
    }
#pragma unroll
    for (int kk = 0; kk < 2; ++kk) {
      bf16x8 af[4], bv[6];
#pragma unroll
      for (int mi = 0; mi < 4; ++mi) {
        const int p = (wr * 64 + mi * 16 + l15) * 128 + kk * 64 + l4 * 16;
        af[mi] = *(const bf16x8*)(bufA + swz128(p));
      }
#pragma unroll
      for (int ni = 0; ni < 6; ++ni) {
        const int p = (wc * 96 + ni * 16 + l15) * 128 + kk * 64 + l4 * 16;
        bv[ni] = *(const bf16x8*)(bufB + swz128(p));
      }
#pragma unroll
      for (int mi = 0; mi < 4; ++mi)
#pragma unroll
        for (int ni = 0; ni < 6; ++ni)
          acc[mi][ni] = __builtin_amdgcn_mfma_f32_16x16x32_bf16(af[mi], bv[ni], acc[mi][ni], 0, 0, 0);
    }

    if (t + 1 < NT) {
      asm volatile("s_waitcnt vmcnt(0)" ::: "memory");
      __builtin_amdgcn_s_barrier();
    }
  }

#pragma unroll
  for (int mi = 0; mi < 4; ++mi)
#pragma unroll
    for (int ni = 0; ni < 6; ++ni)
#pragma unroll
      for (int r = 0; r < 4; ++r) {
        const int row = m0 + wr * 64 + mi * 16 + l4 * 4 + r;
        const int col = n0 + wc * 96 + ni * 16 + l15;
        outp[(size_t)row * HDIM + col] = f2bf(acc[mi][ni][r]);
      }
}

// ---------------------------------------------------------------- attention one q-tile (wave-private)
DEVFN void attn_one(const ushort_t* __restrict__ qr, const ushort_t* __restrict__ kr,
                    const ushort_t* __restrict__ vT, ushort_t* __restrict__ ab,
                    int h, int seg, int qt, ushort_t* Pw, int l15, int l4) {
  const int qrow0 = seg * SEGLEN + qt * 16;
  bf16x8 aq[2];
#pragma unroll
  for (int kk = 0; kk < 2; ++kk)
    aq[kk] = *(const bf16x8*)(qr + ((size_t)h * N_TOK + qrow0 + l15) * HD + kk * 32 + l4 * 8);

  f32x4 o[4] = {};
  float m_run[4], l_run[4];
#pragma unroll
  for (int r = 0; r < 4; ++r) { m_run[r] = -1e30f; l_run[r] = 0.f; }

  const int kbmax = qt >> 2;
  for (int kb = 0; kb <= kbmax; ++kb) {
    bf16x8 bk[4][2];
#pragma unroll
    for (int ni = 0; ni < 4; ++ni)
#pragma unroll
      for (int kk = 0; kk < 2; ++kk)
        bk[ni][kk] = *(const bf16x8*)(kr + ((size_t)h * N_TOK + seg * SEGLEN + kb * 64 + ni * 16 + l15) * HD + kk * 32 + l4 * 8);
    f32x4 s[4] = {};
#pragma unroll
    for (int ni = 0; ni < 4; ++ni)
#pragma unroll
      for (int kk = 0; kk < 2; ++kk)
        s[ni] = __builtin_amdgcn_mfma_f32_16x16x32_bf16(aq[kk], bk[ni][kk], s[ni], 0, 0, 0);

    const bool diag = (kb == kbmax);
#pragma unroll
    for (int ni = 0; ni < 4; ++ni)
#pragma unroll
      for (int r = 0; r < 4; ++r) {
        float v = s[ni][r] * 0.125f;
        if (diag) {
          const int qrow = qt * 16 + l4 * 4 + r;
          const int jcol = kb * 64 + ni * 16 + l15;
          if (jcol > qrow) v = -1e30f;
        }
        s[ni][r] = v;
      }

    float sc_[4];
#pragma unroll
    for (int r = 0; r < 4; ++r) {
      float pm = fmaxf(fmaxf(s[0][r], s[1][r]), fmaxf(s[2][r], s[3][r]));
      pm = fmaxf(pm, __shfl_xor(pm, 1));
      pm = fmaxf(pm, __shfl_xor(pm, 2));
      pm = fmaxf(pm, __shfl_xor(pm, 4));
      pm = fmaxf(pm, __shfl_xor(pm, 8));
      const float mn = fmaxf(m_run[r], pm);
      sc_[r] = __expf(m_run[r] - mn);
      m_run[r] = mn;
    }
#pragma unroll
    for (int ni = 0; ni < 4; ++ni)
#pragma unroll
      for (int r = 0; r < 4; ++r)
        s[ni][r] = __expf(s[ni][r] - m_run[r]);
#pragma unroll
    for (int r = 0; r < 4; ++r) {
      float ls = s[0][r] + s[1][r] + s[2][r] + s[3][r];
      ls += __shfl_xor(ls, 1);
      ls += __shfl_xor(ls, 2);
      ls += __shfl_xor(ls, 4);
      ls += __shfl_xor(ls, 8);
      l_run[r] = l_run[r] * sc_[r] + ls;
    }
#pragma unroll
    for (int ni = 0; ni < 4; ++ni)
#pragma unroll
      for (int r = 0; r < 4; ++r)
        o[ni][r] *= sc_[r];

#pragma unroll
    for (int ni = 0; ni < 4; ++ni)
#pragma unroll
      for (int r = 0; r < 4; ++r)
        Pw[(l4 * 4 + r) * 64 + ni * 16 + l15] = f2bf(s[ni][r]);

    bf16x8 pa[2], bv[4][2];
#pragma unroll
    for (int k2 = 0; k2 < 2; ++k2)
      pa[k2] = *(const bf16x8*)(&Pw[l15 * 64 + k2 * 32 + l4 * 8]);
#pragma unroll
    for (int ni = 0; ni < 4; ++ni)
#pragma unroll
      for (int k2 = 0; k2 < 2; ++k2)
        bv[ni][k2] = *(const bf16x8*)(vT + ((size_t)h * HD + ni * 16 + l15) * N_TOK + seg * SEGLEN + kb * 64 + k2 * 32 + l4 * 8);
#pragma unroll
    for (int ni = 0; ni < 4; ++ni)
#pragma unroll
      for (int k2 = 0; k2 < 2; ++k2)
        o[ni] = __builtin_amdgcn_mfma_f32_16x16x32_bf16(pa[k2], bv[ni][k2], o[ni], 0, 0, 0);
  }

#pragma unroll
  for (int ni = 0; ni < 4; ++ni)
#pragma unroll
    for (int r = 0; r < 4; ++r) {
      const int row = qrow0 + l4 * 4 + r;
      const int col = h * HD + ni * 16 + l15;
      ab[(size_t)row * ABCOLS + col] = f2bf(o[ni][r] / l_run[r]);
    }
}

// ---------------------------------------------------------------- fused mid: 448 blocks + extra transposes
__global__ __launch_bounds__(256, 2) void fused_mid(
    const ushort_t* __restrict__ ab, const ushort_t* __restrict__ woutT,
    ushort_t* __restrict__ cpartb,
    const ushort_t* __restrict__ qr, const ushort_t* __restrict__ kr,
    const ushort_t* __restrict__ vT, ushort_t* __restrict__ ab_out,
    const float* __restrict__ tj_src, ushort_t* __restrict__ tj_dst) {
  __shared__ __align__(16) char smem[2 * G2_BUF];     // 80 KiB
  const int b = (int)blockIdx.x;
  const int tid = threadIdx.x;
  if (b >= 448) {
    const int e = b - 448;
    transpose_tile(tj_src, tj_dst, ABCOLS, HDIM, (e / 24) * 64, (e % 24) * 32, tid, smem);
    return;
  }
  const int sel = b % 7;
  if (sel < 3) {
    const int a = (b / 7) * 3 + sel;      // 0..191
    const int h = a % NHEADS;
    const int r2 = a / NHEADS;            // 0..15
    const int seg = r2 & 7, p = r2 >> 3;  // p in {0,1}
    const int w = tid >> 6, l = tid & 63;
    const int l15 = l & 15, l4 = l >> 4;
    ushort_t* Pw = (ushort_t*)smem + w * (16 * 64);
    attn_one(qr, kr, vT, ab_out, h, seg, p * 4 + w, Pw, l15, l4);
    attn_one(qr, kr, vT, ab_out, h, seg, (3 - p) * 4 + w, Pw, l15, l4);
  } else {
    const int f = (b / 7) * 4 + (sel - 3);   // 0..255
    const int z = 1 + (f >> 6);              // ff chunks 1..4
    const int rem = f & 63;
    const int n0 = (rem & 3) * 192, m0 = (rem >> 2) * 128;
    g2_body(ab, woutT, smem, m0, n0, z * KCHUNK, 12,
            cpartb + (size_t)(z - 1) * N_TOK * HDIM, tid);
  }
}

// ---------------------------------------------------------------- gemm2 attn-column chunk (K 0..768, split in 2)
__global__ __launch_bounds__(256, 2) void gemm2_z0(
    const ushort_t* __restrict__ ab, const ushort_t* __restrict__ woutT,
    ushort_t* __restrict__ cpartb) {
  __shared__ __align__(16) char smem[2 * G2_BUF];
  const int b = (int)blockIdx.x;
  const int half = b >> 6, rem = b & 63;
  const int n0 = (rem & 3) * 192, m0 = (rem >> 2) * 128;
  g2_body(ab, woutT, smem, m0, n0, half * 384, 6,
          cpartb + (size_t)(4 + half) * N_TOK * HDIM, threadIdx.x);
}

// ----------------------------------------------------------------
extern "C" void kernel_launch(void* const* d_in, const int* in_sizes, int n_in,
                              void* d_out, int out_size, void* d_ws, size_t ws_size,
                              hipStream_t stream) {
  const int*   tokens   = (const int*)d_in[0];
  const float* ages     = (const float*)d_in[1];
  const float* time_d   = (const float*)d_in[2];
  const float* embed    = (const float*)d_in[4];
  const float* in_nw    = (const float*)d_in[5];
  const float* out_nw   = (const float*)d_in[6];
  const float* layer_nw = (const float*)d_in[7];
  const float* Win      = (const float*)d_in[8];
  const float* Wout     = (const float*)d_in[9];
  float* out = (float*)d_out;

  char* ws = (char*)d_ws;
  float*    x      = (float*)   (ws + 0);            //  6,291,456
  ushort_t* hbuf   = (ushort_t*)(ws + 6291456);      //  3,145,728
  float2*   sctab  = (float2*)  (ws + 9437184);      //  1,048,576
  ushort_t* cpartb = (ushort_t*)(ws + 10485760);     // 18,874,368 (6 bf16 slices)
  ushort_t* ab     = (ushort_t*)(ws + 29360128);     // 15,728,640
  ushort_t* qrb    = (ushort_t*)(ws + 45088768);     //  3,145,728
  ushort_t* krb    = (ushort_t*)(ws + 48234496);     //  3,145,728
  ushort_t* vTb    = (ushort_t*)(ws + 51380224);     //  3,145,728
  ushort_t* winT   = (ushort_t*)(ws + 54525952);     // 25,952,256
  ushort_t* woutT  = (ushort_t*)(ws + 80478208);     // 11,796,480

  const size_t winStride  = (size_t)TCOLS * HDIM;
  const size_t woutStride = (size_t)HDIM * ABCOLS;

  preamble<<<dim3(5216), dim3(256), 0, stream>>>(Win, winT, embed, tokens, ages,
                                                 in_nw, layer_nw, time_d, x, hbuf, sctab);

  for (int lyr = 0; lyr < 2; ++lyr) {
    if (lyr == 0) {
      gemm1f<<<dim3(704 + 4608), dim3(256), 0, stream>>>(
          hbuf, winT, sctab, ab, qrb, krb, vTb,
          Wout, woutT, Win + winStride, winT + winStride);
      fused_mid<<<dim3(448 + 1440), dim3(256), 0, stream>>>(
          ab, woutT, cpartb, qrb, krb, vTb, ab,
          Wout + woutStride, woutT + woutStride);
    } else {
      gemm1f<<<dim3(704), dim3(256), 0, stream>>>(
          hbuf, winT + winStride, sctab, ab, qrb, krb, vTb,
          nullptr, nullptr, nullptr, nullptr);
      fused_mid<<<dim3(448), dim3(256), 0, stream>>>(
          ab, woutT + woutStride, cpartb, qrb, krb, vTb, ab,
          nullptr, nullptr);
    }
    gemm2_z0<<<dim3(128), dim3(256), 0, stream>>>(ab, woutT + lyr * woutStride, cpartb);
    if (lyr == 0)
      rms_fused<<<dim3(N_TOK), dim3(256), 0, stream>>>(cpartb, x, layer_nw + HDIM, time_d,
                                                       nullptr, hbuf, 1);
    else
      rms_fused<<<dim3(N_TOK), dim3(256), 0, stream>>>(cpartb, x, out_nw, nullptr,
                                                       out, nullptr, 2);
  }
}

// Round 16
// 172.477 us; speedup vs baseline: 1.3352x; 1.0752x over previous
//
#include <hip/hip_runtime.h>
#include <math.h>

typedef unsigned short ushort_t;
typedef float f32x4 __attribute__((ext_vector_type(4)));
typedef __bf16 bf16x8 __attribute__((ext_vector_type(8)));

#define DEVFN __device__ __forceinline__

DEVFN ushort_t f2bf(float f) {
  unsigned int u = __float_as_uint(f);
  u += 0x7FFFu + ((u >> 16) & 1u);   // round-to-nearest-even
  return (ushort_t)(u >> 16);
}
DEVFN float bf2f(ushort_t u) { return __uint_as_float((unsigned int)u << 16); }

DEVFN void gload(const ushort_t* src, char* dst) {
  __builtin_amdgcn_global_load_lds(
      (const __attribute__((address_space(1))) unsigned int*)src,
      (__attribute__((address_space(3))) unsigned int*)dst, 16, 0, 0);
}

#define N_TOK  2048
#define HDIM   768
#define TCOLS  8448     // 2*I + 3*H
#define FFI    3072
#define NHEADS 12
#define HD     64
#define NSEG   8
#define SEGLEN 256
#define ABCOLS 3840     // H + I
#define NPART  6
#define KCHUNK 768

// ---------------------------------------------------------------- 64x32 transpose tile
DEVFN void transpose_tile(const float* __restrict__ in, ushort_t* __restrict__ out,
                          int R, int C, int tr, int tc, int tid, char* smem) {
  ushort_t (*tile)[66] = (ushort_t(*)[66])smem;
  const int tx = tid & 31, ty = tid >> 5;   // 32 x 8
#pragma unroll
  for (int i = 0; i < 8; ++i) {
    const int r = ty + i * 8;
    tile[tx][r] = f2bf(in[(size_t)(tr + r) * C + tc + tx]);
  }
  __syncthreads();
#pragma unroll
  for (int i = 0; i < 4; ++i) {
    const int c = ty + i * 8;
    ushort2 pk; pk.x = tile[c][2 * tx]; pk.y = tile[c][2 * tx + 1];
    *(ushort2*)(out + (size_t)(tc + c) * R + tr + 2 * tx) = pk;
  }
}

// ---------------------------------------------------------------- preamble: winT-0 transpose + rms_init
__global__ __launch_bounds__(256) void preamble(
    const float* __restrict__ Win, ushort_t* __restrict__ winT,
    const float* __restrict__ embed, const int* __restrict__ tokens,
    const float* __restrict__ ages,
    const float* __restrict__ in_nw, const float* __restrict__ layer_nw,
    const float* __restrict__ time_data,
    float* __restrict__ x, ushort_t* __restrict__ hbuf, float2* __restrict__ sctab) {
  const int tid = threadIdx.x;
  if (blockIdx.x < 3168) {
    __shared__ char tsmem[32 * 66 * 2];
    const int id = blockIdx.x;
    transpose_tile(Win, winT, HDIM, TCOLS, (id / 264) * 64, (id % 264) * 32, tid, tsmem);
    return;
  }
  const int row = blockIdx.x - 3168;
  if (tid < 32) {
    const int k = tid;
    const float e = (2.0f * (float)k) / 31.0f;
    const float t = ages[row] * expf(-e * logf(10000.0f));
    float2 cs; cs.x = cosf(t); cs.y = sinf(t);
    sctab[row * HD + 2 * k] = cs;
    sctab[row * HD + 2 * k + 1] = cs;
  }
  __shared__ float part[4];
  const float* src = embed + (size_t)tokens[row] * HDIM;
  float4 v = {0.f, 0.f, 0.f, 0.f};
  const int c0 = tid * 4;
  if (tid < 192) v = *(const float4*)(src + c0);
  float ss = v.x * v.x + v.y * v.y + v.z * v.z + v.w * v.w;
#pragma unroll
  for (int off = 1; off < 64; off <<= 1) ss += __shfl_xor(ss, off);
  if ((tid & 63) == 0) part[tid >> 6] = ss;
  __syncthreads();
  const float rs = rsqrtf((part[0] + part[1] + part[2] + part[3]) * (1.0f / HDIM) + 1e-6f);
  float4 y = {0.f, 0.f, 0.f, 0.f};
  if (tid < 192) {
    y.x = v.x * rs * in_nw[c0]; y.y = v.y * rs * in_nw[c0 + 1];
    y.z = v.z * rs * in_nw[c0 + 2]; y.w = v.w * rs * in_nw[c0 + 3];
    *(float4*)(x + (size_t)row * HDIM + c0) = y;
  }
  float ss2 = y.x * y.x + y.y * y.y + y.z * y.z + y.w * y.w;
#pragma unroll
  for (int off = 1; off < 64; off <<= 1) ss2 += __shfl_xor(ss2, off);
  __syncthreads();
  if ((tid & 63) == 0) part[tid >> 6] = ss2;
  __syncthreads();
  const float rs2 = rsqrtf((part[0] + part[1] + part[2] + part[3]) * (1.0f / HDIM) + 1e-6f);
  if (tid < 192) {
    float val[4];
#pragma unroll
    for (int j = 0; j < 4; ++j) {
      const int c = c0 + j;
      float vv = ((const float*)&y)[j] * rs2 * layer_nw[c];
      if (c >= HDIM - 4) {
        const float td = time_data[row * 2 + (c & 1)];
        vv = (c >= HDIM - 2) ? td * td : td;
      }
      val[j] = vv;
    }
    ushort4 pk;
    pk.x = f2bf(val[0]); pk.y = f2bf(val[1]); pk.z = f2bf(val[2]); pk.w = f2bf(val[3]);
    *(ushort4*)(hbuf + (size_t)row * HDIM + c0) = pk;
  }
}

// ---------------------------------------------------------------- fused reduce(6 bf16 partials) + residual + rms
__global__ __launch_bounds__(256) void rms_fused(
    const ushort_t* __restrict__ cpartb, float* __restrict__ x,
    const float* __restrict__ w, const float* __restrict__ time_data,
    float* __restrict__ out_f32, ushort_t* __restrict__ out_bf16, const int mode) {
  const int row = blockIdx.x;
  const size_t stride = (size_t)N_TOK * HDIM;
  const int tid = threadIdx.x;
  const int c0 = tid * 4;
  float4 s = {0.f, 0.f, 0.f, 0.f};
  if (tid < 192) {
    s = *(const float4*)(x + (size_t)row * HDIM + c0);
#pragma unroll
    for (int z = 0; z < NPART; ++z) {
      const ushort4 p = *(const ushort4*)(cpartb + z * stride + (size_t)row * HDIM + c0);
      s.x += bf2f(p.x); s.y += bf2f(p.y); s.z += bf2f(p.z); s.w += bf2f(p.w);
    }
    if (mode == 1) *(float4*)(x + (size_t)row * HDIM + c0) = s;
  }
  float ss = s.x * s.x + s.y * s.y + s.z * s.z + s.w * s.w;
#pragma unroll
  for (int off = 1; off < 64; off <<= 1) ss += __shfl_xor(ss, off);
  __shared__ float part[4];
  if ((tid & 63) == 0) part[tid >> 6] = ss;
  __syncthreads();
  const float rs = rsqrtf((part[0] + part[1] + part[2] + part[3]) * (1.0f / HDIM) + 1e-6f);
  if (tid < 192) {
    float val[4];
#pragma unroll
    for (int j = 0; j < 4; ++j) {
      const int c = c0 + j;
      float vv = ((const float*)&s)[j] * rs * w[c];
      if (mode == 1 && c >= HDIM - 4) {
        const float td = time_data[row * 2 + (c & 1)];
        vv = (c >= HDIM - 2) ? td * td : td;
      }
      val[j] = vv;
    }
    if (mode == 1) {
      ushort4 pk;
      pk.x = f2bf(val[0]); pk.y = f2bf(val[1]); pk.z = f2bf(val[2]); pk.w = f2bf(val[3]);
      *(ushort4*)(out_bf16 + (size_t)row * HDIM + c0) = pk;
    } else {
      float4 o; o.x = val[0]; o.y = val[1]; o.z = val[2]; o.w = val[3];
      *(float4*)(out_f32 + (size_t)row * HDIM + c0) = o;
    }
  }
}

// ---------------------------------------------------------------- GEMM1: LDS staging, single-barrier 2-phase loop
#define G1_NT 24
#define G1_ABYT 8192
#define G1_BUF  20480

DEVFN int swz64(int p) {
  const int g = ((p >> 6) & 3) ^ ((p >> 8) & 3);
  return p ^ (g << 4);
}
DEVFN int ffmap(int vr) {
  return (vr < 2 * FFI) ? ((((vr >> 4) & 1) * FFI) + ((vr >> 5) << 4) + (vr & 15)) : vr;
}

DEVFN void g1f_stage(const ushort_t* __restrict__ A, const ushort_t* __restrict__ BT,
                     int m0, int n0, int kt_el, char* buf, int tid) {
#pragma unroll
  for (int i = 0; i < 2; ++i) {
    const int q = swz64(i * 4096 + tid * 16);
    gload(A + (size_t)(m0 + (q >> 6)) * HDIM + kt_el + ((q & 63) >> 1),
          buf + i * 4096 + ((tid >> 6) << 10));
  }
#pragma unroll
  for (int i = 0; i < 3; ++i) {
    const int q = swz64(i * 4096 + tid * 16);
    const int vr = n0 + (q >> 6);
    gload(BT + (size_t)ffmap(vr) * HDIM + kt_el + ((q & 63) >> 1),
          buf + G1_ABYT + i * 4096 + ((tid >> 6) << 10));
  }
}

// extra blocks (bid>=704): e<1440 -> Wout->woutT; else -> Win lyr1 -> winT lyr1
__global__ __launch_bounds__(256, 3) void gemm1f(
    const ushort_t* __restrict__ A, const ushort_t* __restrict__ BT,
    const float2* __restrict__ sctab,
    ushort_t* __restrict__ ab, ushort_t* __restrict__ qr,
    ushort_t* __restrict__ kr, ushort_t* __restrict__ vT,
    const float* __restrict__ tj1_src, ushort_t* __restrict__ tj1_dst,
    const float* __restrict__ tj2_src, ushort_t* __restrict__ tj2_dst) {
  __shared__ __align__(16) char smem[2 * G1_BUF];
  const int tid = threadIdx.x;
  const int bid = (int)blockIdx.x;
  if (bid >= 704) {
    int e = bid - 704;
    if (e < 1440)
      transpose_tile(tj1_src, tj1_dst, ABCOLS, HDIM, (e / 24) * 64, (e % 24) * 32, tid, smem);
    else {
      e -= 1440;
      transpose_tile(tj2_src, tj2_dst, HDIM, TCOLS, (e / 264) * 64, (e % 264) * 32, tid, smem);
    }
    return;
  }
  const int l = tid & 63, l15 = l & 15, l4 = l >> 4;
  const int wid = tid >> 6, wr = wid >> 1, wc = wid & 1;
  const int wg = (bid & 7) * 88 + (bid >> 3);
  const int nt = wg >> 4, mt = wg & 15;
  const int m0 = mt * 128, n0 = nt * 192;

  f32x4 acc[4][6] = {};

  // prologue: stage tile 0, wait, barrier
  g1f_stage(A, BT, m0, n0, 0, smem, tid);
  asm volatile("s_waitcnt vmcnt(0)" ::: "memory");
  __builtin_amdgcn_s_barrier();

  for (int t = 0; t < G1_NT; ++t) {
    const char* bufA = smem + (t & 1) * G1_BUF;
    const char* bufB = bufA + G1_ABYT;
    // issue next tile's staging first (hides under this tile's compute)
    if (t + 1 < G1_NT) {
      g1f_stage(A, BT, m0, n0, (t + 1) * 32, smem + ((t + 1) & 1) * G1_BUF, tid);
      __builtin_amdgcn_sched_barrier(0);
    }
    bf16x8 a4[4], b6[6];
#pragma unroll
    for (int m = 0; m < 4; ++m) {
      const int p = (wr * 64 + m * 16 + l15) * 64 + l4 * 16;
      a4[m] = *(const bf16x8*)(bufA + swz64(p));
    }
#pragma unroll
    for (int n = 0; n < 6; ++n) {
      const int p = (wc * 96 + n * 16 + l15) * 64 + l4 * 16;
      b6[n] = *(const bf16x8*)(bufB + swz64(p));
    }
#pragma unroll
    for (int m = 0; m < 4; ++m)
#pragma unroll
      for (int n = 0; n < 6; ++n)
        acc[m][n] = __builtin_amdgcn_mfma_f32_16x16x32_bf16(a4[m], b6[n], acc[m][n], 0, 0, 0);

    if (t + 1 < G1_NT) {
      asm volatile("s_waitcnt vmcnt(0)" ::: "memory");   // next tile landed
      __builtin_amdgcn_s_barrier();                      // all reads of buf[t&1] done
    }
  }

  if (nt < 32) {
#pragma unroll
    for (int m = 0; m < 4; ++m)
#pragma unroll
      for (int np = 0; np < 3; ++np) {
        const int colj = (nt * 6 + wc * 3 + np) * 16 + l15;
#pragma unroll
        for (int r = 0; r < 4; ++r) {
          const float x1 = acc[m][2 * np][r], x2 = acc[m][2 * np + 1][r];
          const float sv = x1 / (1.f + __expf(-x1)) * x2;
          const int row = m0 + wr * 64 + m * 16 + l4 * 4 + r;
          ab[(size_t)row * ABCOLS + HDIM + colj] = f2bf(sv);
        }
      }
  } else {
#pragma unroll
    for (int n = 0; n < 6; ++n) {
      const int gcol = (nt - 32) * 192 + wc * 96 + n * 16;
      const int g = gcol >> 6;
      const int typ = g / NHEADS, h = g - typ * NHEADS;
      const int d = (gcol & 63) + l15;
      if (typ == 2) {
#pragma unroll
        for (int m = 0; m < 4; ++m) {
          ushort4 pk;
          pk.x = f2bf(acc[m][n][0]); pk.y = f2bf(acc[m][n][1]);
          pk.z = f2bf(acc[m][n][2]); pk.w = f2bf(acc[m][n][3]);
          const int row0 = m0 + wr * 64 + m * 16 + l4 * 4;
          *(ushort4*)(vT + ((size_t)h * HD + d) * N_TOK + row0) = pk;
        }
      } else {
        ushort_t* dst = (typ == 0) ? qr : kr;
        const float sgn = (l15 & 1) ? 1.f : -1.f;
#pragma unroll
        for (int m = 0; m < 4; ++m)
#pragma unroll
          for (int r = 0; r < 4; ++r) {
            const float val = acc[m][n][r];
            const float partner = __shfl_xor(val, 1);
            const int row = m0 + wr * 64 + m * 16 + l4 * 4 + r;
            const float2 cs = sctab[row * HD + d];
            dst[((size_t)h * N_TOK + row) * HD + d] = f2bf(val * cs.x + sgn * partner * cs.y);
          }
      }
    }
  }
}

// ---------------------------------------------------------------- GEMM2 body: 128x192, BK=64, single-barrier 2-phase
#define G2_BUF 40960          // A 16KB + B 24KB

DEVFN int swz128(int p) { return p ^ (((p >> 7) & 7) << 4); }

DEVFN void g2_stage(const ushort_t* __restrict__ A, const ushort_t* __restrict__ BT,
                    int m0, int n0, int kt_el, char* buf, int tid) {
#pragma unroll
  for (int i = 0; i < 10; ++i) {
    const int p = i * 4096 + tid * 16;
    const bool isA = p < 16384;
    const int q = swz128(isA ? p : p - 16384);
    const int row = q >> 7, colel = (q & 127) >> 1;
    const ushort_t* src = (isA ? A + (size_t)(m0 + row) * ABCOLS
                               : BT + (size_t)(n0 + row) * ABCOLS) + kt_el + colel;
    gload(src, buf + i * 4096 + ((tid >> 6) << 10));
  }
}

DEVFN void g2_body(const ushort_t* __restrict__ A, const ushort_t* __restrict__ BT,
                   char* smem, int m0, int n0, int kt0, int NT,
                   ushort_t* __restrict__ outp, int tid) {
  const int l = tid & 63, l15 = l & 15, l4 = l >> 4;
  const int w = tid >> 6, wr = w >> 1, wc = w & 1;
  f32x4 acc[4][6] = {};

  g2_stage(A, BT, m0, n0, kt0, smem, tid);
  asm volatile("s_waitcnt vmcnt(0)" ::: "memory");
  __builtin_amdgcn_s_barrier();

  for (int t = 0; t < NT; ++t) {
    const char* bufA = smem + (t & 1) * G2_BUF;
    const char* bufB = bufA + 16384;
    if (t + 1 < NT) {
      g2_stage(A, BT, m0, n0, kt0 + (t + 1) * 64, smem + ((t + 1) & 1) * G2_BUF, tid);
      __builtin_amdgcn_sched_barrier(0);
    }
#pragma unroll
    for (int kk = 0; kk < 2; ++kk) {
      bf16x8 af[4], bv[6];
#pragma unroll
      for (int mi = 0; mi < 4; ++mi) {
        const int p = (wr * 64 + mi * 16 + l15) * 128 + kk * 64 + l4 * 16;
        af[mi] = *(const bf16x8*)(bufA + swz128(p));
      }
#pragma unroll
      for (int ni = 0; ni < 6; ++ni) {
        const int p = (wc * 96 + ni * 16 + l15) * 128 + kk * 64 + l4 * 16;
        bv[ni] = *(const bf16x8*)(bufB + swz128(p));
      }
#pragma unroll
      for (int mi = 0; mi < 4; ++mi)
#pragma unroll
        for (int ni = 0; ni < 6; ++ni)
          acc[mi][ni] = __builtin_amdgcn_mfma_f32_16x16x32_bf16(af[mi], bv[ni], acc[mi][ni], 0, 0, 0);
    }

    if (t + 1 < NT) {
      asm volatile("s_waitcnt vmcnt(0)" ::: "memory");
      __builtin_amdgcn_s_barrier();
    }
  }

#pragma unroll
  for (int mi = 0; mi < 4; ++mi)
#pragma unroll
    for (int ni = 0; ni < 6; ++ni)
#pragma unroll
      for (int r = 0; r < 4; ++r) {
        const int row = m0 + wr * 64 + mi * 16 + l4 * 4 + r;
        const int col = n0 + wc * 96 + ni * 16 + l15;
        outp[(size_t)row * HDIM + col] = f2bf(acc[mi][ni][r]);
      }
}

// ---------------------------------------------------------------- attention one q-tile (wave-private)
DEVFN void attn_one(const ushort_t* __restrict__ qr, const ushort_t* __restrict__ kr,
                    const ushort_t* __restrict__ vT, ushort_t* __restrict__ ab,
                    int h, int seg, int qt, ushort_t* Pw, int l15, int l4) {
  const int qrow0 = seg * SEGLEN + qt * 16;
  bf16x8 aq[2];
#pragma unroll
  for (int kk = 0; kk < 2; ++kk)
    aq[kk] = *(const bf16x8*)(qr + ((size_t)h * N_TOK + qrow0 + l15) * HD + kk * 32 + l4 * 8);

  f32x4 o[4] = {};
  float m_run[4], l_run[4];
#pragma unroll
  for (int r = 0; r < 4; ++r) { m_run[r] = -1e30f; l_run[r] = 0.f; }

  const int kbmax = qt >> 2;
  for (int kb = 0; kb <= kbmax; ++kb) {
    bf16x8 bk[4][2];
#pragma unroll
    for (int ni = 0; ni < 4; ++ni)
#pragma unroll
      for (int kk = 0; kk < 2; ++kk)
        bk[ni][kk] = *(const bf16x8*)(kr + ((size_t)h * N_TOK + seg * SEGLEN + kb * 64 + ni * 16 + l15) * HD + kk * 32 + l4 * 8);
    f32x4 s[4] = {};
#pragma unroll
    for (int ni = 0; ni < 4; ++ni)
#pragma unroll
      for (int kk = 0; kk < 2; ++kk)
        s[ni] = __builtin_amdgcn_mfma_f32_16x16x32_bf16(aq[kk], bk[ni][kk], s[ni], 0, 0, 0);

    const bool diag = (kb == kbmax);
#pragma unroll
    for (int ni = 0; ni < 4; ++ni)
#pragma unroll
      for (int r = 0; r < 4; ++r) {
        float v = s[ni][r] * 0.125f;
        if (diag) {
          const int qrow = qt * 16 + l4 * 4 + r;
          const int jcol = kb * 64 + ni * 16 + l15;
          if (jcol > qrow) v = -1e30f;
        }
        s[ni][r] = v;
      }

    float sc_[4];
#pragma unroll
    for (int r = 0; r < 4; ++r) {
      float pm = fmaxf(fmaxf(s[0][r], s[1][r]), fmaxf(s[2][r], s[3][r]));
      pm = fmaxf(pm, __shfl_xor(pm, 1));
      pm = fmaxf(pm, __shfl_xor(pm, 2));
      pm = fmaxf(pm, __shfl_xor(pm, 4));
      pm = fmaxf(pm, __shfl_xor(pm, 8));
      const float mn = fmaxf(m_run[r], pm);
      sc_[r] = __expf(m_run[r] - mn);
      m_run[r] = mn;
    }
#pragma unroll
    for (int ni = 0; ni < 4; ++ni)
#pragma unroll
      for (int r = 0; r < 4; ++r)
        s[ni][r] = __expf(s[ni][r] - m_run[r]);
#pragma unroll
    for (int r = 0; r < 4; ++r) {
      float ls = s[0][r] + s[1][r] + s[2][r] + s[3][r];
      ls += __shfl_xor(ls, 1);
      ls += __shfl_xor(ls, 2);
      ls += __shfl_xor(ls, 4);
      ls += __shfl_xor(ls, 8);
      l_run[r] = l_run[r] * sc_[r] + ls;
    }
#pragma unroll
    for (int ni = 0; ni < 4; ++ni)
#pragma unroll
      for (int r = 0; r < 4; ++r)
        o[ni][r] *= sc_[r];

#pragma unroll
    for (int ni = 0; ni < 4; ++ni)
#pragma unroll
      for (int r = 0; r < 4; ++r)
        Pw[(l4 * 4 + r) * 64 + ni * 16 + l15] = f2bf(s[ni][r]);

    bf16x8 pa[2], bv[4][2];
#pragma unroll
    for (int k2 = 0; k2 < 2; ++k2)
      pa[k2] = *(const bf16x8*)(&Pw[l15 * 64 + k2 * 32 + l4 * 8]);
#pragma unroll
    for (int ni = 0; ni < 4; ++ni)
#pragma unroll
      for (int k2 = 0; k2 < 2; ++k2)
        bv[ni][k2] = *(const bf16x8*)(vT + ((size_t)h * HD + ni * 16 + l15) * N_TOK + seg * SEGLEN + kb * 64 + k2 * 32 + l4 * 8);
#pragma unroll
    for (int ni = 0; ni < 4; ++ni)
#pragma unroll
      for (int k2 = 0; k2 < 2; ++k2)
        o[ni] = __builtin_amdgcn_mfma_f32_16x16x32_bf16(pa[k2], bv[ni][k2], o[ni], 0, 0, 0);
  }

#pragma unroll
  for (int ni = 0; ni < 4; ++ni)
#pragma unroll
    for (int r = 0; r < 4; ++r) {
      const int row = qrow0 + l4 * 4 + r;
      const int col = h * HD + ni * 16 + l15;
      ab[(size_t)row * ABCOLS + col] = f2bf(o[ni][r] / l_run[r]);
    }
}

// ---------------------------------------------------------------- fused mid: 448 blocks (b%7<3 attn, else gemm2) + extra transposes
__global__ __launch_bounds__(256, 2) void fused_mid(
    const ushort_t* __restrict__ ab, const ushort_t* __restrict__ woutT,
    ushort_t* __restrict__ cpartb,
    const ushort_t* __restrict__ qr, const ushort_t* __restrict__ kr,
    const ushort_t* __restrict__ vT, ushort_t* __restrict__ ab_out,
    const float* __restrict__ tj_src, ushort_t* __restrict__ tj_dst) {
  __shared__ __align__(16) char smem[2 * G2_BUF];     // 80 KiB
  const int b = (int)blockIdx.x;
  const int tid = threadIdx.x;
  if (b >= 448) {
    const int e = b - 448;
    transpose_tile(tj_src, tj_dst, ABCOLS, HDIM, (e / 24) * 64, (e % 24) * 32, tid, smem);
    return;
  }
  const int sel = b % 7;
  if (sel < 3) {
    const int a = (b / 7) * 3 + sel;      // 0..191
    const int h = a % NHEADS;
    const int r2 = a / NHEADS;            // 0..15
    const int seg = r2 & 7, p = r2 >> 3;  // p in {0,1}
    const int w = tid >> 6, l = tid & 63;
    const int l15 = l & 15, l4 = l >> 4;
    ushort_t* Pw = (ushort_t*)smem + w * (16 * 64);
    attn_one(qr, kr, vT, ab_out, h, seg, p * 4 + w, Pw, l15, l4);
    attn_one(qr, kr, vT, ab_out, h, seg, (3 - p) * 4 + w, Pw, l15, l4);
  } else {
    const int f = (b / 7) * 4 + (sel - 3);   // 0..255
    const int z = 1 + (f >> 6);              // ff chunks 1..4
    const int rem = f & 63;
    const int n0 = (rem & 3) * 192, m0 = (rem >> 2) * 128;
    g2_body(ab, woutT, smem, m0, n0, z * KCHUNK, 12,
            cpartb + (size_t)(z - 1) * N_TOK * HDIM, tid);
  }
}

// ---------------------------------------------------------------- gemm2 attn-column chunk (K 0..768, split in 2)
__global__ __launch_bounds__(256, 2) void gemm2_z0(
    const ushort_t* __restrict__ ab, const ushort_t* __restrict__ woutT,
    ushort_t* __restrict__ cpartb) {
  __shared__ __align__(16) char smem[2 * G2_BUF];
  const int b = (int)blockIdx.x;
  const int half = b >> 6, rem = b & 63;
  const int n0 = (rem & 3) * 192, m0 = (rem >> 2) * 128;
  g2_body(ab, woutT, smem, m0, n0, half * 384, 6,
          cpartb + (size_t)(4 + half) * N_TOK * HDIM, threadIdx.x);
}

// ----------------------------------------------------------------
extern "C" void kernel_launch(void* const* d_in, const int* in_sizes, int n_in,
                              void* d_out, int out_size, void* d_ws, size_t ws_size,
                              hipStream_t stream) {
  const int*   tokens   = (const int*)d_in[0];
  const float* ages     = (const float*)d_in[1];
  const float* time_d   = (const float*)d_in[2];
  const float* embed    = (const float*)d_in[4];
  const float* in_nw    = (const float*)d_in[5];
  const float* out_nw   = (const float*)d_in[6];
  const float* layer_nw = (const float*)d_in[7];
  const float* Win      = (const float*)d_in[8];
  const float* Wout     = (const float*)d_in[9];
  float* out = (float*)d_out;

  char* ws = (char*)d_ws;
  float*    x      = (float*)   (ws + 0);            //  6,291,456
  ushort_t* hbuf   = (ushort_t*)(ws + 6291456);      //  3,145,728
  float2*   sctab  = (float2*)  (ws + 9437184);      //  1,048,576
  ushort_t* cpartb = (ushort_t*)(ws + 10485760);     // 18,874,368 (6 bf16 slices)
  ushort_t* ab     = (ushort_t*)(ws + 29360128);     // 15,728,640
  ushort_t* qrb    = (ushort_t*)(ws + 45088768);     //  3,145,728
  ushort_t* krb    = (ushort_t*)(ws + 48234496);     //  3,145,728
  ushort_t* vTb    = (ushort_t*)(ws + 51380224);     //  3,145,728
  ushort_t* winT   = (ushort_t*)(ws + 54525952);     // 25,952,256
  ushort_t* woutT  = (ushort_t*)(ws + 80478208);     // 11,796,480

  const size_t winStride  = (size_t)TCOLS * HDIM;
  const size_t woutStride = (size_t)HDIM * ABCOLS;

  preamble<<<dim3(5216), dim3(256), 0, stream>>>(Win, winT, embed, tokens, ages,
                                                 in_nw, layer_nw, time_d, x, hbuf, sctab);

  for (int lyr = 0; lyr < 2; ++lyr) {
    if (lyr == 0) {
      gemm1f<<<dim3(704 + 4608), dim3(256), 0, stream>>>(
          hbuf, winT, sctab, ab, qrb, krb, vTb,
          Wout, woutT, Win + winStride, winT + winStride);
      fused_mid<<<dim3(448 + 1440), dim3(256), 0, stream>>>(
          ab, woutT, cpartb, qrb, krb, vTb, ab,
          Wout + woutStride, woutT + woutStride);
    } else {
      gemm1f<<<dim3(704), dim3(256), 0, stream>>>(
          hbuf, winT + winStride, sctab, ab, qrb, krb, vTb,
          nullptr, nullptr, nullptr, nullptr);
      fused_mid<<<dim3(448), dim3(256), 0, stream>>>(
          ab, woutT + woutStride, cpartb, qrb, krb, vTb, ab,
          nullptr, nullptr);
    }
    gemm2_z0<<<dim3(128), dim3(256), 0, stream>>>(ab, woutT + lyr * woutStride, cpartb);
    if (lyr == 0)
      rms_fused<<<dim3(N_TOK), dim3(256), 0, stream>>>(cpartb, x, layer_nw + HDIM, time_d,
                                                       nullptr, hbuf, 1);
    else
      rms_fused<<<dim3(N_TOK), dim3(256), 0, stream>>>(cpartb, x, out_nw, nullptr,
                                                       out, nullptr, 2);
  }
}